// Round 8
// baseline (23938.055 us; speedup 1.0000x reference)
//
#include <hip/hip_runtime.h>
#include <hip/hip_fp16.h>

#define N_ 256
#define C_ 3
#define T_ 300
#define V_ 25
#define H_ 256
#define G4_ 1024   // 4*H
#define IN_ 75
#define XP1_ 96    // padded input-K
#define NCLS_ 60

typedef _Float16 half_t;
typedef __attribute__((ext_vector_type(8))) _Float16 half8;
typedef __attribute__((ext_vector_type(4))) float f32x4;
typedef __attribute__((ext_vector_type(2))) unsigned int uint2v;

static_assert(sizeof(half8) == 16, "half8 must be 16B");

__device__ __forceinline__ float sigm(float x) { return 1.0f / (1.0f + __expf(-x)); }
__device__ __forceinline__ float tanh_f(float x) {
  x = fminf(fmaxf(x, -15.0f), 15.0f);
  float e = __expf(2.0f * x);
  return (e - 1.0f) / (e + 1.0f);
}

// ---------- pack [Whh | Wih | 0pad] rows into fp16, bias = bih+bhh ----------
__global__ void pack_wcat(const float* __restrict__ Whh, const float* __restrict__ Wih,
                          const float* __restrict__ bih, const float* __restrict__ bhh,
                          half_t* __restrict__ dstW, float* __restrict__ dstB,
                          int inDim, int Kc) {
  int idx = blockIdx.x * 256 + threadIdx.x;
  int tot = G4_ * Kc;
  if (idx < tot) {
    int row = idx / Kc, k = idx % Kc;
    float v = 0.0f;
    if (k < H_) v = Whh[row * H_ + k];
    else if (k - H_ < inDim) v = Wih[row * inDim + (k - H_)];
    dstW[idx] = (half_t)v;
  }
  if (idx < G4_) dstB[idx] = bih[idx] + bhh[idx];
}

// ---------- pack x -> seqb[p][n][t][96] fp16 ----------
__global__ void pack_seq(const float* __restrict__ x, half_t* __restrict__ seqb) {
  int idx = blockIdx.x * 256 + threadIdx.x;
  const int tot = 2 * N_ * T_ * XP1_;
  if (idx >= tot) return;
  int k = idx % XP1_; int r = idx / XP1_;
  int t = r % T_; int r2 = r / T_;
  int n = r2 % N_; int p = r2 / N_;
  float v = 0.0f;
  if (k < IN_) {
    int c = k / V_, vv = k % V_;
    v = x[(((size_t)n * C_ + c) * T_ + t) * (V_ * 2) + vv * 2 + p];
  }
  seqb[idx] = (half_t)v;
}

// ---------- monolithic LSTM: full hidden state in one 1024-thread WG ----------
// WG = (run, 16-sample tile). wave w owns units w*16..w*16+15 x all 4 gates
// (gates = the 4 MFMA n-tiles -> no cross-lane gate gather). Weights in VGPRs.
// h/x exchanged through XOR-swizzled LDS double buffers; ONE barrier per step.
template<int KT>
__global__ __launch_bounds__(1024, 1) void lstm_mono(
    const half_t* __restrict__ W0, const half_t* __restrict__ W1,
    const float* __restrict__ b0, const float* __restrict__ b1,
    const half_t* __restrict__ xseq,
    half_t* __restrict__ hseq,
    float* __restrict__ hlast0, float* __restrict__ hlast1) {
  constexpr int XKT = KT - 8;
  constexpr int XK = XKT * 32;                 // 96 or 256
  constexpr int XKP = (XK <= 96) ? 128 : 256;  // swizzle-safe padded row
  constexpr int Kc = KT * 32;

  const int tile = blockIdx.x & 31;
  const int run = blockIdx.x >> 5;
  const int row0 = tile * 16;
  const int tid = threadIdx.x;
  const int w = tid >> 6, lane = tid & 63;
  const int col = lane & 15, khalf = lane >> 4, klo8 = khalf * 8;
  const int u = w * 16 + col;

  const half_t* __restrict__ Wcat = run ? W1 : W0;
  const float* __restrict__ bias = run ? b1 : b0;
  float* hlast = run ? hlast1 : hlast0;

  __shared__ __align__(16) half_t hpan[2][16 * 256];
  __shared__ __align__(16) half_t xpan[2][16 * XKP];

  // ---- weights + bias -> registers: wave w, gate g covers row g*256+u ----
  half8 wreg[4][KT];
  float brg[4];
#pragma unroll
  for (int g = 0; g < 4; ++g) {
    int grow = g * 256 + u;
    brg[g] = bias[grow];
#pragma unroll
    for (int kt = 0; kt < KT; ++kt)
      wreg[g][kt] = *reinterpret_cast<const half8*>(Wcat + (size_t)grow * Kc + kt * 32 + klo8);
  }

  // ---- x staging slots: 4 halfs (8B) per thread, coalesced ----
  const int sflat = tid * 4;
  const bool sact = sflat < 16 * XK;
  const int ss = sact ? (sflat / XK) : 0;
  const int sk = sact ? (sflat % XK) : 0;
  const int xoff = ss * XKP + (sk ^ ((ss & 7) << 3));
  const half_t* xsrc = xseq + (size_t)(row0 + ss) * T_ * XK + sk;

  // ---- prologue: h0 = 0; stage x(0) ----
  for (int i = tid; i < 16 * 256; i += 1024) hpan[0][i] = (half_t)0;
  if (sact)
    *reinterpret_cast<uint2v*>(&xpan[0][xoff]) =
        *reinterpret_cast<const uint2v*>(xsrc);
  float creg[4] = {};
  __syncthreads();

#pragma unroll 1
  for (int t = 0; t < T_; ++t) {
    const int cur = t & 1, nxt = cur ^ 1;

    // prefetch x(t+1) to regs (written to LDS pre-barrier)
    uint2v xs = {};
    const bool pf = sact && (t + 1 < T_);
    if (pf) xs = *reinterpret_cast<const uint2v*>(xsrc + (size_t)(t + 1) * XK);

    // A fragments from swizzled LDS
    half8 a[KT];
#pragma unroll
    for (int kt = 0; kt < 8; ++kt)
      a[kt] = *reinterpret_cast<const half8*>(
          &hpan[cur][col * 256 + ((kt * 32 + klo8) ^ ((col & 7) << 3))]);
#pragma unroll
    for (int kx = 0; kx < XKT; ++kx)
      a[8 + kx] = *reinterpret_cast<const half8*>(
          &xpan[cur][col * XKP + ((kx * 32 + klo8) ^ ((col & 7) << 3))]);

    // MFMA: 4 gates x KT k-chunks
    f32x4 acc[4];
#pragma unroll
    for (int g = 0; g < 4; ++g) acc[g] = (f32x4){brg[g], brg[g], brg[g], brg[g]};
#pragma unroll
    for (int kt = 0; kt < KT; ++kt)
#pragma unroll
      for (int g = 0; g < 4; ++g)
        acc[g] = __builtin_amdgcn_mfma_f32_16x16x32_f16(a[kt], wreg[g][kt], acc[g], 0, 0, 0);

    // activations: all 4 gates lane-local; cell state = 4 regs
#pragma unroll
    for (int r = 0; r < 4; ++r) {
      const int s = khalf * 4 + r;
      float iv = sigm(acc[0][r]);
      float fv = sigm(acc[1][r]);
      float gv = tanh_f(acc[2][r]);
      float ov = sigm(acc[3][r]);
      float c = fv * creg[r] + iv * gv;
      creg[r] = c;
      float h = ov * tanh_f(c);
      hpan[nxt][s * 256 + (u ^ ((s & 7) << 3))] = (half_t)h;
      if (hlast != nullptr && t == T_ - 1)
        hlast[(size_t)(row0 + s) * H_ + u] = h;
    }
    if (pf)
      *reinterpret_cast<uint2v*>(&xpan[nxt][xoff]) = xs;
    __syncthreads();

    // coalesced hseq write from the fresh h panel
    if (hseq != nullptr) {
      const int cs = tid >> 6, ck = (tid & 63) * 4;
      uint2v v = *reinterpret_cast<const uint2v*>(
          &hpan[nxt][cs * 256 + (ck ^ ((cs & 7) << 3))]);
      *reinterpret_cast<uint2v*>(
          &hseq[((size_t)(row0 + cs) * T_ + t) * H_ + ck]) = v;
    }
  }
}

// ---------- angles/trans FC + rotation matrices ----------
__global__ void fc3_rot(const float* __restrict__ hrot, const float* __restrict__ htr,
                        const float* __restrict__ rfcW, const float* __restrict__ rfcb,
                        const float* __restrict__ tfcW, const float* __restrict__ tfcb,
                        float* __restrict__ rt) {
  int idx = blockIdx.x * blockDim.x + threadIdx.x;
  if (idx >= 2 * N_) return;
  const float* h1 = hrot + (size_t)idx * H_;
  const float* h2 = htr + (size_t)idx * H_;
  float ang[3], tr[3];
#pragma unroll
  for (int i = 0; i < 3; ++i) {
    float a = rfcb[i], b = tfcb[i];
    for (int j = 0; j < H_; ++j) { a += h1[j] * rfcW[i * H_ + j]; b += h2[j] * tfcW[i * H_ + j]; }
    ang[i] = a * 3.14159265358979323846f;
    tr[i] = b;
  }
  float c0 = cosf(ang[0]), s0 = sinf(ang[0]);
  float c1 = cosf(ang[1]), s1 = sinf(ang[1]);
  float c2 = cosf(ang[2]), s2 = sinf(ang[2]);
  float Rx[3][3] = {{1, 0, 0}, {0, c0, s0}, {0, -s0, c0}};
  float Ry[3][3] = {{c1, 0, -s1}, {0, 1, 0}, {s1, 0, c1}};
  float Rz[3][3] = {{c2, s2, 0}, {-s2, c2, 0}, {0, 0, 1}};
  float A[3][3], R[3][3];
  for (int i = 0; i < 3; ++i)
    for (int j = 0; j < 3; ++j) {
      float s = 0;
      for (int k = 0; k < 3; ++k) s += Rx[i][k] * Ry[k][j];
      A[i][j] = s;
    }
  for (int i = 0; i < 3; ++i)
    for (int j = 0; j < 3; ++j) {
      float s = 0;
      for (int k = 0; k < 3; ++k) s += A[i][k] * Rz[k][j];
      R[i][j] = s;
    }
  float* o = rt + (size_t)idx * 12;
  for (int i = 0; i < 9; ++i) o[i] = R[i / 3][i % 3];
  for (int i = 0; i < 3; ++i) o[9 + i] = tr[i];
}

// ---------- seq2 = R @ (x - trans), overwrites seqb ----------
__global__ void transform_seq(const float* __restrict__ x, const float* __restrict__ rt,
                              half_t* __restrict__ seqb) {
  int idx = blockIdx.x * 256 + threadIdx.x;
  const int tot = 2 * N_ * T_ * V_;
  if (idx >= tot) return;
  int v = idx % V_; int r = idx / V_;
  int t = r % T_; int r2 = r / T_;
  int n = r2 % N_; int p = r2 / N_;
  const float* o = rt + ((size_t)p * N_ + n) * 12;
  float xv[3];
#pragma unroll
  for (int c = 0; c < 3; ++c)
    xv[c] = x[(((size_t)n * C_ + c) * T_ + t) * (V_ * 2) + v * 2 + p] - o[9 + c];
  size_t base = (((size_t)p * N_ + n) * T_ + t) * XP1_;
#pragma unroll
  for (int i = 0; i < 3; ++i) {
    float s = o[i * 3 + 0] * xv[0] + o[i * 3 + 1] * xv[1] + o[i * 3 + 2] * xv[2];
    seqb[base + i * V_ + v] = (half_t)s;
  }
}

// ---------- maxpool over persons + final FC ----------
__global__ void final_fc(const float* __restrict__ hM2, const float* __restrict__ fcW,
                         const float* __restrict__ fcb, float* __restrict__ out) {
  int n = blockIdx.x;
  __shared__ float hm[H_];
  for (int j = threadIdx.x; j < H_; j += blockDim.x)
    hm[j] = fmaxf(hM2[(size_t)n * H_ + j], hM2[(size_t)(N_ + n) * H_ + j]);
  __syncthreads();
  if (threadIdx.x < NCLS_) {
    float acc = fcb[threadIdx.x];
    for (int j = 0; j < H_; ++j) acc += hm[j] * fcW[threadIdx.x * H_ + j];
    out[n * NCLS_ + threadIdx.x] = acc;
  }
}

extern "C" void kernel_launch(void* const* d_in, const int* in_sizes, int n_in,
                              void* d_out, int out_size, void* d_ws, size_t ws_size,
                              hipStream_t stream) {
  const float* x       = (const float*)d_in[0];
  const float* rot_Wih = (const float*)d_in[1];
  const float* rot_Whh = (const float*)d_in[2];
  const float* rot_bih = (const float*)d_in[3];
  const float* rot_bhh = (const float*)d_in[4];
  const float* rot_fcW = (const float*)d_in[5];
  const float* rot_fcb = (const float*)d_in[6];
  const float* tr_Wih  = (const float*)d_in[7];
  const float* tr_Whh  = (const float*)d_in[8];
  const float* tr_bih  = (const float*)d_in[9];
  const float* tr_bhh  = (const float*)d_in[10];
  const float* tr_fcW  = (const float*)d_in[11];
  const float* tr_fcb  = (const float*)d_in[12];
  const float* m0_Wih  = (const float*)d_in[13];
  const float* m0_Whh  = (const float*)d_in[14];
  const float* m0_bih  = (const float*)d_in[15];
  const float* m0_bhh  = (const float*)d_in[16];
  const float* m1_Wih  = (const float*)d_in[17];
  const float* m1_Whh  = (const float*)d_in[18];
  const float* m1_bih  = (const float*)d_in[19];
  const float* m1_bhh  = (const float*)d_in[20];
  const float* m2_Wih  = (const float*)d_in[21];
  const float* m2_Whh  = (const float*)d_in[22];
  const float* m2_bih  = (const float*)d_in[23];
  const float* m2_bhh  = (const float*)d_in[24];
  const float* fcW     = (const float*)d_in[25];
  const float* fcb     = (const float*)d_in[26];

  char* ws = (char*)d_ws;
  size_t off = 0;
  auto take = [&](size_t b) -> void* {
    void* pp = ws + off;
    off = (off + b + 255) & ~(size_t)255;
    return pp;
  };
  half_t* WC_ROT = (half_t*)take((size_t)G4_ * 352 * 2);
  half_t* WC_TR  = (half_t*)take((size_t)G4_ * 352 * 2);
  half_t* WC_M0  = (half_t*)take((size_t)G4_ * 352 * 2);
  half_t* WC_M1  = (half_t*)take((size_t)G4_ * 512 * 2);
  half_t* WC_M2  = (half_t*)take((size_t)G4_ * 512 * 2);
  float* B_ROT = (float*)take((size_t)G4_ * 4);
  float* B_TR  = (float*)take((size_t)G4_ * 4);
  float* B_M0  = (float*)take((size_t)G4_ * 4);
  float* B_M1  = (float*)take((size_t)G4_ * 4);
  float* B_M2  = (float*)take((size_t)G4_ * 4);
  half_t* SEQB = (half_t*)take((size_t)2 * N_ * T_ * XP1_ * 2);
  float* HL_ROT = (float*)take((size_t)2 * N_ * H_ * 4);
  float* HL_TR  = (float*)take((size_t)2 * N_ * H_ * 4);
  float* HL_M2  = (float*)take((size_t)2 * N_ * H_ * 4);
  float* RT     = (float*)take((size_t)2 * N_ * 12 * 4);
  half_t* HS0 = (half_t*)take((size_t)2 * N_ * T_ * H_ * 2);
  half_t* HS1 = (half_t*)take((size_t)2 * N_ * T_ * H_ * 2);

  // ---- pack weights (fp16) + fused biases ----
  pack_wcat<<<1408, 256, 0, stream>>>(rot_Whh, rot_Wih, rot_bih, rot_bhh, WC_ROT, B_ROT, IN_, 352);
  pack_wcat<<<1408, 256, 0, stream>>>(tr_Whh, tr_Wih, tr_bih, tr_bhh, WC_TR, B_TR, IN_, 352);
  pack_wcat<<<1408, 256, 0, stream>>>(m0_Whh, m0_Wih, m0_bih, m0_bhh, WC_M0, B_M0, IN_, 352);
  pack_wcat<<<2048, 256, 0, stream>>>(m1_Whh, m1_Wih, m1_bih, m1_bhh, WC_M1, B_M1, H_, 512);
  pack_wcat<<<2048, 256, 0, stream>>>(m2_Whh, m2_Wih, m2_bih, m2_bhh, WC_M2, B_M2, H_, 512);

  pack_seq<<<(2 * N_ * T_ * XP1_ + 255) / 256, 256, 0, stream>>>(x, SEQB);

  // ---- phase 1: rot (run0) & tr (run1) fused: 2 runs x 32 tiles = 64 WGs ----
  lstm_mono<11><<<64, 1024, 0, stream>>>(
      WC_ROT, WC_TR, B_ROT, B_TR, SEQB, nullptr, HL_ROT, HL_TR);

  fc3_rot<<<2, 256, 0, stream>>>(HL_ROT, HL_TR, rot_fcW, rot_fcb, tr_fcW, tr_fcb, RT);
  transform_seq<<<(2 * N_ * T_ * V_ + 255) / 256, 256, 0, stream>>>(x, RT, SEQB);

  // ---- stacked main LSTMs: 32 WGs each, zero cross-WG traffic ----
  lstm_mono<11><<<32, 1024, 0, stream>>>(
      WC_M0, WC_M0, B_M0, B_M0, SEQB, HS0, nullptr, nullptr);
  lstm_mono<16><<<32, 1024, 0, stream>>>(
      WC_M1, WC_M1, B_M1, B_M1, HS0, HS1, nullptr, nullptr);
  lstm_mono<16><<<32, 1024, 0, stream>>>(
      WC_M2, WC_M2, B_M2, B_M2, HS1, nullptr, HL_M2, HL_M2);

  final_fc<<<256, 64, 0, stream>>>(HL_M2, fcW, fcb, (float*)d_out);
}

// Round 10
// 10392.580 us; speedup vs baseline: 2.3034x; 2.3034x over previous
//
#include <hip/hip_runtime.h>
#include <hip/hip_fp16.h>

#define N_ 256
#define C_ 3
#define T_ 300
#define V_ 25
#define H_ 256
#define G4_ 1024   // 4*H
#define IN_ 75
#define XP1_ 96    // padded input-K
#define NCLS_ 60

typedef _Float16 half_t;
typedef __attribute__((ext_vector_type(8))) _Float16 half8;
typedef __attribute__((ext_vector_type(4))) float f32x4;
typedef __attribute__((ext_vector_type(4))) unsigned int uint4v;
typedef __attribute__((ext_vector_type(2))) unsigned int uint2v;

static_assert(sizeof(half8) == 16, "half8 must be 16B");

__device__ __forceinline__ float tanh_f(float x) {
  x = fminf(fmaxf(x, -15.0f), 15.0f);
  float e = __expf(2.0f * x);
  return (e - 1.0f) / (e + 1.0f);
}

// ---- MALL-coherent ops (PROVEN rounds 3/5/6): bypass non-coherent L1/L2 ----
__device__ __forceinline__ half8 gload16_cc(const void* p) {
  uint4v r;
  asm volatile("global_load_dwordx4 %0, %1, off sc0 sc1" : "=v"(r) : "v"(p));
  return __builtin_bit_cast(half8, r);
}
__device__ __forceinline__ void store8_cc(void* p, uint2v v) {
  asm volatile("global_store_dwordx2 %0, %1, off sc0 sc1" :: "v"(p), "v"(v) : "memory");
}
__device__ __forceinline__ void waitvm0() {
  asm volatile("s_waitcnt vmcnt(0)" ::: "memory");
  __builtin_amdgcn_sched_barrier(0);
}

// ---------- pack [Whh | Wih | 0pad] rows into fp16, bias = bih+bhh ----------
__global__ void pack_wcat(const float* __restrict__ Whh, const float* __restrict__ Wih,
                          const float* __restrict__ bih, const float* __restrict__ bhh,
                          half_t* __restrict__ dstW, float* __restrict__ dstB,
                          int inDim, int Kc) {
  int idx = blockIdx.x * 256 + threadIdx.x;
  int tot = G4_ * Kc;
  if (idx < tot) {
    int row = idx / Kc, k = idx % Kc;
    float v = 0.0f;
    if (k < H_) v = Whh[row * H_ + k];
    else if (k - H_ < inDim) v = Wih[row * inDim + (k - H_)];
    dstW[idx] = (half_t)v;
  }
  if (idx < G4_) dstB[idx] = bih[idx] + bhh[idx];
}

// ---------- pack x -> seqb[p][n][t][96] fp16 ----------
__global__ void pack_seq(const float* __restrict__ x, half_t* __restrict__ seqb) {
  int idx = blockIdx.x * 256 + threadIdx.x;
  const int tot = 2 * N_ * T_ * XP1_;
  if (idx >= tot) return;
  int k = idx % XP1_; int r = idx / XP1_;
  int t = r % T_; int r2 = r / T_;
  int n = r2 % N_; int p = r2 / N_;
  float v = 0.0f;
  if (k < IN_) {
    int c = k / V_, vv = k % V_;
    v = x[(((size_t)n * C_ + c) * T_ + t) * (V_ * 2) + vv * 2 + p];
  }
  seqb[idx] = (half_t)v;
}

// ---------- one LSTM layer, sentinel data-poll at MALL scope ----------
// group = 32 sample rows x 8 members (32-unit gate slices). Weights in VGPRs.
// h via depth-3 ring [slot][member][rr][32]; consumers poll data for 0xFFFF
// sentinels (h = sigm*tanh in (-1,1) can never be 0xFFFF = fp16 -NaN).
// If POLLX: x panel (prev layer's hseq, write-once, pre-sentineled) is also
// polled -> enables cross-layer wavefront pipelining within one dispatch.
template<int KT, bool POLLX>
__device__ __forceinline__ void run_layer(
    const half_t* __restrict__ Wcat, const float* __restrict__ bias,
    const half_t* __restrict__ xseq,
    half_t* __restrict__ ring, int rr,
    half_t* __restrict__ hseq, float* __restrict__ hlast,
    int ringRow0, int seqRow0, int u0, int member,
    half_t* hstage) {
  constexpr int XKT = KT - 8;
  constexpr int XK = XKT * 32;
  constexpr int Kc = KT * 32;
  const int tid = threadIdx.x, lane = tid & 63, wave = tid >> 6;
  const int col = lane & 15, khalf = lane >> 4, klo8 = khalf * 8, gq = col & 3;
  const int srow = tid >> 3, spart = tid & 7;

  // ---- weights + bias -> registers (validated fragment layout) ----
  half8 wreg[2][KT];
  float brg[2];
#pragma unroll
  for (int ntp = 0; ntp < 2; ++ntp) {
    int lrow = (wave * 2 + ntp) * 16 + col;
    int grow = (lrow & 3) * 256 + u0 + (lrow >> 2);
#pragma unroll
    for (int kt = 0; kt < KT; ++kt)
      wreg[ntp][kt] = *reinterpret_cast<const half8*>(Wcat + (size_t)grow * Kc + kt * 32 + klo8);
    brg[ntp] = bias[grow];
  }

  const half_t* xrow[2];
#pragma unroll
  for (int c = 0; c < 2; ++c)
    xrow[c] = xseq + (size_t)(seqRow0 + c * 16 + col) * T_ * XK + klo8;

  float creg[2][2][4] = {};

  auto chk = [](half8 v) -> unsigned {
    uint4v u = __builtin_bit_cast(uint4v, v);
    return ((u[0] & 0xFFFFu) == 0xFFFFu) | ((u[1] & 0xFFFFu) == 0xFFFFu) |
           ((u[2] & 0xFFFFu) == 0xFFFFu) | ((u[3] & 0xFFFFu) == 0xFFFFu);
  };

#pragma unroll 1
  for (int t = 0; t < T_; ++t) {
    const int sc_ = t % 3;
    const int sp_ = (t + 2) % 3;
    const int sn_ = (t + 1) % 3;
    const bool hasH = (t > 0);

    half8 ax[2][XKT];
    half8 ah[2][8];

    if (!POLLX) {
      // x from a fully-materialized buffer: plain cached loads
#pragma unroll
      for (int c = 0; c < 2; ++c)
#pragma unroll
        for (int kx = 0; kx < XKT; ++kx)
          ax[c][kx] = *reinterpret_cast<const half8*>(xrow[c] + (size_t)t * XK + kx * 32);
    }

    if (hasH || POLLX) {
      int guard = 0;
      for (;;) {
        if (hasH) {
#pragma unroll
          for (int c = 0; c < 2; ++c)
#pragma unroll
            for (int kt = 0; kt < 8; ++kt)
              ah[c][kt] = gload16_cc(
                  ring + ((size_t)(sp_ * 8 + kt) * rr + ringRow0 + c * 16 + col) * 32 + klo8);
        }
        if (POLLX) {
#pragma unroll
          for (int c = 0; c < 2; ++c)
#pragma unroll
            for (int kx = 0; kx < XKT; ++kx)
              ax[c][kx] = gload16_cc(xrow[c] + (size_t)t * XK + kx * 32);
        }
        waitvm0();
        unsigned bad = 0;
        if (hasH) {
#pragma unroll
          for (int c = 0; c < 2; ++c)
#pragma unroll
            for (int kt = 0; kt < 8; ++kt) bad |= chk(ah[c][kt]);
        }
        if (POLLX) {
#pragma unroll
          for (int c = 0; c < 2; ++c)
#pragma unroll
            for (int kx = 0; kx < XKT; ++kx) bad |= chk(ax[c][kx]);
        }
        if (__all(bad == 0u)) break;
        if (++guard > (1 << 20)) break;  // bounded failure, no hang
        __builtin_amdgcn_s_sleep(1);
      }
      // Orders previous step's hstage publish-read BEFORE this step's
      // hstage writes across all waves (race fix vs round 9).
      __syncthreads();
      __builtin_amdgcn_sched_barrier(0);
    }

    // ---- sentinel own region of NEXT slot (post-poll; drained pre-publish) ----
    {
      uint2v sent = {0xFFFFFFFFu, 0xFFFFFFFFu};
      store8_cc(ring + ((size_t)(sn_ * 8 + member) * rr + ringRow0 + srow) * 32 + spart * 4, sent);
    }

    // ---- MFMA + activations for both 16-row chunks ----
#pragma unroll
    for (int c = 0; c < 2; ++c) {
      f32x4 acc[2];
      acc[0] = (f32x4){brg[0], brg[0], brg[0], brg[0]};
      acc[1] = (f32x4){brg[1], brg[1], brg[1], brg[1]};
      if (hasH) {
#pragma unroll
        for (int kt = 0; kt < 8; ++kt) {
          acc[0] = __builtin_amdgcn_mfma_f32_16x16x32_f16(ah[c][kt], wreg[0][kt], acc[0], 0, 0, 0);
          acc[1] = __builtin_amdgcn_mfma_f32_16x16x32_f16(ah[c][kt], wreg[1][kt], acc[1], 0, 0, 0);
        }
      }
#pragma unroll
      for (int kx = 0; kx < XKT; ++kx) {
        acc[0] = __builtin_amdgcn_mfma_f32_16x16x32_f16(ax[c][kx], wreg[0][8 + kx], acc[0], 0, 0, 0);
        acc[1] = __builtin_amdgcn_mfma_f32_16x16x32_f16(ax[c][kx], wreg[1][8 + kx], acc[1], 0, 0, 0);
      }
#pragma unroll
      for (int ntp = 0; ntp < 2; ++ntp) {
        int nt = wave * 2 + ntp;
        int ul = nt * 4 + (col >> 2);
#pragma unroll
        for (int r = 0; r < 4; ++r) {
          float v = acc[ntp][r];
          float y = (gq == 2) ? 2.0f * v : v;
          float s = 1.0f / (1.0f + __expf(-y));
          float av = (gq == 2) ? (2.0f * s - 1.0f) : s;
          float b1v = __shfl_xor(av, 1);
          float b2v = __shfl_xor(av, 2);
          float b3v = __shfl_xor(b1v, 2);
          auto pick = [&](int k2) { return k2 == 0 ? av : (k2 == 1 ? b1v : (k2 == 2 ? b2v : b3v)); };
          float iv = pick(gq), fv = pick(gq ^ 1), gv = pick(gq ^ 2), ov = pick(gq ^ 3);
          float cc = fv * creg[c][ntp][r] + iv * gv;
          creg[c][ntp][r] = cc;
          float h = ov * tanh_f(cc);
          if (gq == 0) {
            int s_ = c * 16 + khalf * 4 + r;
            hstage[s_ * 32 + ul] = (half_t)h;
            if (hlast != nullptr && t == T_ - 1)
              hlast[(size_t)(seqRow0 + s_) * H_ + u0 + ul] = h;
          }
        }
      }
    }
    __syncthreads();

    // ---- drain sentinels, then publish h (ring + pipelined hseq) ----
    waitvm0();
    {
      uint2v val = *reinterpret_cast<const uint2v*>(&hstage[srow * 32 + spart * 4]);
      store8_cc(ring + ((size_t)(sc_ * 8 + member) * rr + ringRow0 + srow) * 32 + spart * 4, val);
      if (hseq)
        store8_cc(&hseq[((size_t)(seqRow0 + srow) * T_ + t) * H_ + u0 + spart * 4], val);
    }
  }
}

// ---------- phase 1: rot (run0) & tr (run1), 32 groups x 8 members ----------
__global__ __launch_bounds__(256, 1) void lstm_p1(
    const half_t* __restrict__ W0, const half_t* __restrict__ W1,
    const float* __restrict__ b0, const float* __restrict__ b1,
    const half_t* __restrict__ xseq, half_t* __restrict__ ring,
    float* __restrict__ hl0, float* __restrict__ hl1) {
  __shared__ __align__(8) half_t hstage[32 * 32];
  const int member = blockIdx.x >> 5;
  const int g = blockIdx.x & 31;
  const int run = g >> 4;
  run_layer<11, false>(run ? W1 : W0, run ? b1 : b0, xseq,
                       ring, 1024, nullptr, run ? hl1 : hl0,
                       g * 32, g * 32 - run * 512, member * 32, member, hstage);
}

// ---------- fused m0/m1/m2: 3-layer wavefront pipeline, 384 blocks ----------
// Co-residency REQUIRED and guaranteed: <=256 VGPR (launch_bounds min 2
// waves/EU), 2 KB LDS -> 2 blocks/CU -> 384 < 512 all resident. Deps are
// forward-only (m1 polls m0's write-once HS0 rows), so pipeline fills ~2 steps.
__global__ __launch_bounds__(256, 2) void lstm_ml(
    const half_t* __restrict__ Wm0, const float* __restrict__ Bm0,
    const half_t* __restrict__ Wm1, const float* __restrict__ Bm1,
    const half_t* __restrict__ Wm2, const float* __restrict__ Bm2,
    const half_t* __restrict__ seqb, half_t* __restrict__ hs0, half_t* __restrict__ hs1,
    half_t* __restrict__ ring0, half_t* __restrict__ ring1, half_t* __restrict__ ring2,
    float* __restrict__ hlast2) {
  __shared__ __align__(8) half_t hstage[32 * 32];
  const int L = blockIdx.x >> 7;
  const int r = blockIdx.x & 127;
  const int member = r >> 4;
  const int g = r & 15;
  const int row0 = g * 32, u0 = member * 32;
  if (L == 0)
    run_layer<11, false>(Wm0, Bm0, seqb, ring0, 512, hs0, nullptr, row0, row0, u0, member, hstage);
  else if (L == 1)
    run_layer<16, true>(Wm1, Bm1, hs0, ring1, 512, hs1, nullptr, row0, row0, u0, member, hstage);
  else
    run_layer<16, true>(Wm2, Bm2, hs1, ring2, 512, nullptr, hlast2, row0, row0, u0, member, hstage);
}

// ---------- angles/trans FC + rotation matrices ----------
__global__ void fc3_rot(const float* __restrict__ hrot, const float* __restrict__ htr,
                        const float* __restrict__ rfcW, const float* __restrict__ rfcb,
                        const float* __restrict__ tfcW, const float* __restrict__ tfcb,
                        float* __restrict__ rt) {
  int idx = blockIdx.x * blockDim.x + threadIdx.x;
  if (idx >= 2 * N_) return;
  const float* h1 = hrot + (size_t)idx * H_;
  const float* h2 = htr + (size_t)idx * H_;
  float ang[3], tr[3];
#pragma unroll
  for (int i = 0; i < 3; ++i) {
    float a = rfcb[i], b = tfcb[i];
    for (int j = 0; j < H_; ++j) { a += h1[j] * rfcW[i * H_ + j]; b += h2[j] * tfcW[i * H_ + j]; }
    ang[i] = a * 3.14159265358979323846f;
    tr[i] = b;
  }
  float c0 = cosf(ang[0]), s0 = sinf(ang[0]);
  float c1 = cosf(ang[1]), s1 = sinf(ang[1]);
  float c2 = cosf(ang[2]), s2 = sinf(ang[2]);
  float Rx[3][3] = {{1, 0, 0}, {0, c0, s0}, {0, -s0, c0}};
  float Ry[3][3] = {{c1, 0, -s1}, {0, 1, 0}, {s1, 0, c1}};
  float Rz[3][3] = {{c2, s2, 0}, {-s2, c2, 0}, {0, 0, 1}};
  float A[3][3], R[3][3];
  for (int i = 0; i < 3; ++i)
    for (int j = 0; j < 3; ++j) {
      float s = 0;
      for (int k = 0; k < 3; ++k) s += Rx[i][k] * Ry[k][j];
      A[i][j] = s;
    }
  for (int i = 0; i < 3; ++i)
    for (int j = 0; j < 3; ++j) {
      float s = 0;
      for (int k = 0; k < 3; ++k) s += A[i][k] * Rz[k][j];
      R[i][j] = s;
    }
  float* o = rt + (size_t)idx * 12;
  for (int i = 0; i < 9; ++i) o[i] = R[i / 3][i % 3];
  for (int i = 0; i < 3; ++i) o[9 + i] = tr[i];
}

// ---------- seq2 = R @ (x - trans), overwrites seqb ----------
__global__ void transform_seq(const float* __restrict__ x, const float* __restrict__ rt,
                              half_t* __restrict__ seqb) {
  int idx = blockIdx.x * 256 + threadIdx.x;
  const int tot = 2 * N_ * T_ * V_;
  if (idx >= tot) return;
  int v = idx % V_; int r = idx / V_;
  int t = r % T_; int r2 = r / T_;
  int n = r2 % N_; int p = r2 / N_;
  const float* o = rt + ((size_t)p * N_ + n) * 12;
  float xv[3];
#pragma unroll
  for (int c = 0; c < 3; ++c)
    xv[c] = x[(((size_t)n * C_ + c) * T_ + t) * (V_ * 2) + v * 2 + p] - o[9 + c];
  size_t base = (((size_t)p * N_ + n) * T_ + t) * XP1_;
#pragma unroll
  for (int i = 0; i < 3; ++i) {
    float s = o[i * 3 + 0] * xv[0] + o[i * 3 + 1] * xv[1] + o[i * 3 + 2] * xv[2];
    seqb[base + i * V_ + v] = (half_t)s;
  }
}

// ---------- maxpool over persons + final FC ----------
__global__ void final_fc(const float* __restrict__ hM2, const float* __restrict__ fcW,
                         const float* __restrict__ fcb, float* __restrict__ out) {
  int n = blockIdx.x;
  __shared__ float hm[H_];
  for (int j = threadIdx.x; j < H_; j += blockDim.x)
    hm[j] = fmaxf(hM2[(size_t)n * H_ + j], hM2[(size_t)(N_ + n) * H_ + j]);
  __syncthreads();
  if (threadIdx.x < NCLS_) {
    float acc = fcb[threadIdx.x];
    for (int j = 0; j < H_; ++j) acc += hm[j] * fcW[threadIdx.x * H_ + j];
    out[n * NCLS_ + threadIdx.x] = acc;
  }
}

extern "C" void kernel_launch(void* const* d_in, const int* in_sizes, int n_in,
                              void* d_out, int out_size, void* d_ws, size_t ws_size,
                              hipStream_t stream) {
  const float* x       = (const float*)d_in[0];
  const float* rot_Wih = (const float*)d_in[1];
  const float* rot_Whh = (const float*)d_in[2];
  const float* rot_bih = (const float*)d_in[3];
  const float* rot_bhh = (const float*)d_in[4];
  const float* rot_fcW = (const float*)d_in[5];
  const float* rot_fcb = (const float*)d_in[6];
  const float* tr_Wih  = (const float*)d_in[7];
  const float* tr_Whh  = (const float*)d_in[8];
  const float* tr_bih  = (const float*)d_in[9];
  const float* tr_bhh  = (const float*)d_in[10];
  const float* tr_fcW  = (const float*)d_in[11];
  const float* tr_fcb  = (const float*)d_in[12];
  const float* m0_Wih  = (const float*)d_in[13];
  const float* m0_Whh  = (const float*)d_in[14];
  const float* m0_bih  = (const float*)d_in[15];
  const float* m0_bhh  = (const float*)d_in[16];
  const float* m1_Wih  = (const float*)d_in[17];
  const float* m1_Whh  = (const float*)d_in[18];
  const float* m1_bih  = (const float*)d_in[19];
  const float* m1_bhh  = (const float*)d_in[20];
  const float* m2_Wih  = (const float*)d_in[21];
  const float* m2_Whh  = (const float*)d_in[22];
  const float* m2_bih  = (const float*)d_in[23];
  const float* m2_bhh  = (const float*)d_in[24];
  const float* fcW     = (const float*)d_in[25];
  const float* fcb     = (const float*)d_in[26];

  char* ws = (char*)d_ws;
  size_t off = 0;
  auto take = [&](size_t b) -> void* {
    void* pp = ws + off;
    off = (off + b + 255) & ~(size_t)255;
    return pp;
  };
  half_t* WC_ROT = (half_t*)take((size_t)G4_ * 352 * 2);
  half_t* WC_TR  = (half_t*)take((size_t)G4_ * 352 * 2);
  half_t* WC_M0  = (half_t*)take((size_t)G4_ * 352 * 2);
  half_t* WC_M1  = (half_t*)take((size_t)G4_ * 512 * 2);
  half_t* WC_M2  = (half_t*)take((size_t)G4_ * 512 * 2);
  float* B_ROT = (float*)take((size_t)G4_ * 4);
  float* B_TR  = (float*)take((size_t)G4_ * 4);
  float* B_M0  = (float*)take((size_t)G4_ * 4);
  float* B_M1  = (float*)take((size_t)G4_ * 4);
  float* B_M2  = (float*)take((size_t)G4_ * 4);
  half_t* SEQB = (half_t*)take((size_t)2 * N_ * T_ * XP1_ * 2);
  float* HL_ROT = (float*)take((size_t)2 * N_ * H_ * 4);
  float* HL_TR  = (float*)take((size_t)2 * N_ * H_ * 4);
  float* HL_M2  = (float*)take((size_t)2 * N_ * H_ * 4);
  float* RT     = (float*)take((size_t)2 * N_ * 12 * 4);
  half_t* RINGP  = (half_t*)take((size_t)3 * 8 * 1024 * 32 * 2);
  half_t* RINGM0 = (half_t*)take((size_t)3 * 8 * 512 * 32 * 2);
  half_t* RINGM1 = (half_t*)take((size_t)3 * 8 * 512 * 32 * 2);
  half_t* RINGM2 = (half_t*)take((size_t)3 * 8 * 512 * 32 * 2);
  half_t* HS0 = (half_t*)take((size_t)2 * N_ * T_ * H_ * 2);
  half_t* HS1 = (half_t*)take((size_t)2 * N_ * T_ * H_ * 2);

  // pre-sentinel rings AND pipelined hseq buffers (0xFF == fp16 0xFFFF)
  hipMemsetAsync(RINGP, 0xFF, (size_t)3 * 8 * 1024 * 32 * 2, stream);
  hipMemsetAsync(RINGM0, 0xFF, (size_t)3 * 8 * 512 * 32 * 2, stream);
  hipMemsetAsync(RINGM1, 0xFF, (size_t)3 * 8 * 512 * 32 * 2, stream);
  hipMemsetAsync(RINGM2, 0xFF, (size_t)3 * 8 * 512 * 32 * 2, stream);
  hipMemsetAsync(HS0, 0xFF, (size_t)2 * N_ * T_ * H_ * 2, stream);
  hipMemsetAsync(HS1, 0xFF, (size_t)2 * N_ * T_ * H_ * 2, stream);

  // ---- pack weights (fp16) + fused biases ----
  pack_wcat<<<1408, 256, 0, stream>>>(rot_Whh, rot_Wih, rot_bih, rot_bhh, WC_ROT, B_ROT, IN_, 352);
  pack_wcat<<<1408, 256, 0, stream>>>(tr_Whh, tr_Wih, tr_bih, tr_bhh, WC_TR, B_TR, IN_, 352);
  pack_wcat<<<1408, 256, 0, stream>>>(m0_Whh, m0_Wih, m0_bih, m0_bhh, WC_M0, B_M0, IN_, 352);
  pack_wcat<<<2048, 256, 0, stream>>>(m1_Whh, m1_Wih, m1_bih, m1_bhh, WC_M1, B_M1, H_, 512);
  pack_wcat<<<2048, 256, 0, stream>>>(m2_Whh, m2_Wih, m2_bih, m2_bhh, WC_M2, B_M2, H_, 512);

  pack_seq<<<(2 * N_ * T_ * XP1_ + 255) / 256, 256, 0, stream>>>(x, SEQB);

  // ---- phase 1: rot & tr (proven MALL-scope sentinel protocol) ----
  lstm_p1<<<256, 256, 0, stream>>>(WC_ROT, WC_TR, B_ROT, B_TR, SEQB, RINGP, HL_ROT, HL_TR);

  fc3_rot<<<2, 256, 0, stream>>>(HL_ROT, HL_TR, rot_fcW, rot_fcb, tr_fcW, tr_fcb, RT);
  transform_seq<<<(2 * N_ * T_ * V_ + 255) / 256, 256, 0, stream>>>(x, RT, SEQB);

  // ---- fused m0/m1/m2 wavefront pipeline (384 blocks, forward-only deps) ----
  lstm_ml<<<384, 256, 0, stream>>>(
      WC_M0, B_M0, WC_M1, B_M1, WC_M2, B_M2,
      SEQB, HS0, HS1, RINGM0, RINGM1, RINGM2, HL_M2);

  final_fc<<<256, 64, 0, stream>>>(HL_M2, fcW, fcb, (float*)d_out);
}

// Round 11
// 6801.766 us; speedup vs baseline: 3.5194x; 1.5279x over previous
//
#include <hip/hip_runtime.h>
#include <hip/hip_fp16.h>

#define N_ 256
#define C_ 3
#define T_ 300
#define V_ 25
#define H_ 256
#define G4_ 1024   // 4*H
#define IN_ 75
#define XP1_ 96    // padded input-K
#define NCLS_ 60

typedef _Float16 half_t;
typedef __attribute__((ext_vector_type(8))) _Float16 half8;
typedef __attribute__((ext_vector_type(4))) float f32x4;
typedef __attribute__((ext_vector_type(4))) unsigned int uint4v;
typedef __attribute__((ext_vector_type(2))) unsigned int uint2v;

static_assert(sizeof(half8) == 16, "half8 must be 16B");

__device__ __forceinline__ float tanh_f(float x) {
  x = fminf(fmaxf(x, -15.0f), 15.0f);
  float e = __expf(2.0f * x);
  return (e - 1.0f) / (e + 1.0f);
}

// ---- MALL-coherent ops (PROVEN rounds 3/5/6): bypass non-coherent L1/L2 ----
__device__ __forceinline__ half8 gload16_cc(const void* p) {
  uint4v r;
  asm volatile("global_load_dwordx4 %0, %1, off sc0 sc1" : "=v"(r) : "v"(p));
  return __builtin_bit_cast(half8, r);
}
__device__ __forceinline__ void store8_cc(void* p, uint2v v) {
  asm volatile("global_store_dwordx2 %0, %1, off sc0 sc1" :: "v"(p), "v"(v) : "memory");
}
__device__ __forceinline__ void waitvm0() {
  asm volatile("s_waitcnt vmcnt(0)" ::: "memory");
  __builtin_amdgcn_sched_barrier(0);
}

// ---------- pack [Whh | Wih | 0pad] rows into fp16, bias = bih+bhh ----------
__global__ void pack_wcat(const float* __restrict__ Whh, const float* __restrict__ Wih,
                          const float* __restrict__ bih, const float* __restrict__ bhh,
                          half_t* __restrict__ dstW, float* __restrict__ dstB,
                          int inDim, int Kc) {
  int idx = blockIdx.x * 256 + threadIdx.x;
  int tot = G4_ * Kc;
  if (idx < tot) {
    int row = idx / Kc, k = idx % Kc;
    float v = 0.0f;
    if (k < H_) v = Whh[row * H_ + k];
    else if (k - H_ < inDim) v = Wih[row * inDim + (k - H_)];
    dstW[idx] = (half_t)v;
  }
  if (idx < G4_) dstB[idx] = bih[idx] + bhh[idx];
}

// ---------- pack x -> seqb[p][n][t][96] fp16 ----------
__global__ void pack_seq(const float* __restrict__ x, half_t* __restrict__ seqb) {
  int idx = blockIdx.x * 256 + threadIdx.x;
  const int tot = 2 * N_ * T_ * XP1_;
  if (idx >= tot) return;
  int k = idx % XP1_; int r = idx / XP1_;
  int t = r % T_; int r2 = r / T_;
  int n = r2 % N_; int p = r2 / N_;
  float v = 0.0f;
  if (k < IN_) {
    int c = k / V_, vv = k % V_;
    v = x[(((size_t)n * C_ + c) * T_ + t) * (V_ * 2) + vv * 2 + p];
  }
  seqb[idx] = (half_t)v;
}

// ========== phase-1 layer (UNCHANGED, proven round 10): sentinel poll ==========
template<int KT, bool POLLX>
__device__ __forceinline__ void run_layer(
    const half_t* __restrict__ Wcat, const float* __restrict__ bias,
    const half_t* __restrict__ xseq,
    half_t* __restrict__ ring, int rr,
    half_t* __restrict__ hseq, float* __restrict__ hlast,
    int ringRow0, int seqRow0, int u0, int member,
    half_t* hstage) {
  constexpr int XKT = KT - 8;
  constexpr int XK = XKT * 32;
  constexpr int Kc = KT * 32;
  const int tid = threadIdx.x, lane = tid & 63, wave = tid >> 6;
  const int col = lane & 15, khalf = lane >> 4, klo8 = khalf * 8, gq = col & 3;
  const int srow = tid >> 3, spart = tid & 7;

  half8 wreg[2][KT];
  float brg[2];
#pragma unroll
  for (int ntp = 0; ntp < 2; ++ntp) {
    int lrow = (wave * 2 + ntp) * 16 + col;
    int grow = (lrow & 3) * 256 + u0 + (lrow >> 2);
#pragma unroll
    for (int kt = 0; kt < KT; ++kt)
      wreg[ntp][kt] = *reinterpret_cast<const half8*>(Wcat + (size_t)grow * Kc + kt * 32 + klo8);
    brg[ntp] = bias[grow];
  }

  const half_t* xrow[2];
#pragma unroll
  for (int c = 0; c < 2; ++c)
    xrow[c] = xseq + (size_t)(seqRow0 + c * 16 + col) * T_ * XK + klo8;

  float creg[2][2][4] = {};

  auto chk = [](half8 v) -> unsigned {
    uint4v u = __builtin_bit_cast(uint4v, v);
    return ((u[0] & 0xFFFFu) == 0xFFFFu) | ((u[1] & 0xFFFFu) == 0xFFFFu) |
           ((u[2] & 0xFFFFu) == 0xFFFFu) | ((u[3] & 0xFFFFu) == 0xFFFFu);
  };

#pragma unroll 1
  for (int t = 0; t < T_; ++t) {
    const int sc_ = t % 3;
    const int sp_ = (t + 2) % 3;
    const int sn_ = (t + 1) % 3;
    const bool hasH = (t > 0);

    half8 ax[2][XKT];
    half8 ah[2][8];

    if (!POLLX) {
#pragma unroll
      for (int c = 0; c < 2; ++c)
#pragma unroll
        for (int kx = 0; kx < XKT; ++kx)
          ax[c][kx] = *reinterpret_cast<const half8*>(xrow[c] + (size_t)t * XK + kx * 32);
    }

    if (hasH || POLLX) {
      int guard = 0;
      for (;;) {
        if (hasH) {
#pragma unroll
          for (int c = 0; c < 2; ++c)
#pragma unroll
            for (int kt = 0; kt < 8; ++kt)
              ah[c][kt] = gload16_cc(
                  ring + ((size_t)(sp_ * 8 + kt) * rr + ringRow0 + c * 16 + col) * 32 + klo8);
        }
        if (POLLX) {
#pragma unroll
          for (int c = 0; c < 2; ++c)
#pragma unroll
            for (int kx = 0; kx < XKT; ++kx)
              ax[c][kx] = gload16_cc(xrow[c] + (size_t)t * XK + kx * 32);
        }
        waitvm0();
        unsigned bad = 0;
        if (hasH) {
#pragma unroll
          for (int c = 0; c < 2; ++c)
#pragma unroll
            for (int kt = 0; kt < 8; ++kt) bad |= chk(ah[c][kt]);
        }
        if (POLLX) {
#pragma unroll
          for (int c = 0; c < 2; ++c)
#pragma unroll
            for (int kx = 0; kx < XKT; ++kx) bad |= chk(ax[c][kx]);
        }
        if (__all(bad == 0u)) break;
        if (++guard > (1 << 20)) break;
        __builtin_amdgcn_s_sleep(1);
      }
      __syncthreads();
      __builtin_amdgcn_sched_barrier(0);
    }

    {
      uint2v sent = {0xFFFFFFFFu, 0xFFFFFFFFu};
      store8_cc(ring + ((size_t)(sn_ * 8 + member) * rr + ringRow0 + srow) * 32 + spart * 4, sent);
    }

#pragma unroll
    for (int c = 0; c < 2; ++c) {
      f32x4 acc[2];
      acc[0] = (f32x4){brg[0], brg[0], brg[0], brg[0]};
      acc[1] = (f32x4){brg[1], brg[1], brg[1], brg[1]};
      if (hasH) {
#pragma unroll
        for (int kt = 0; kt < 8; ++kt) {
          acc[0] = __builtin_amdgcn_mfma_f32_16x16x32_f16(ah[c][kt], wreg[0][kt], acc[0], 0, 0, 0);
          acc[1] = __builtin_amdgcn_mfma_f32_16x16x32_f16(ah[c][kt], wreg[1][kt], acc[1], 0, 0, 0);
        }
      }
#pragma unroll
      for (int kx = 0; kx < XKT; ++kx) {
        acc[0] = __builtin_amdgcn_mfma_f32_16x16x32_f16(ax[c][kx], wreg[0][8 + kx], acc[0], 0, 0, 0);
        acc[1] = __builtin_amdgcn_mfma_f32_16x16x32_f16(ax[c][kx], wreg[1][8 + kx], acc[1], 0, 0, 0);
      }
#pragma unroll
      for (int ntp = 0; ntp < 2; ++ntp) {
        int nt = wave * 2 + ntp;
        int ul = nt * 4 + (col >> 2);
#pragma unroll
        for (int r = 0; r < 4; ++r) {
          float v = acc[ntp][r];
          float y = (gq == 2) ? 2.0f * v : v;
          float s = 1.0f / (1.0f + __expf(-y));
          float av = (gq == 2) ? (2.0f * s - 1.0f) : s;
          float b1v = __shfl_xor(av, 1);
          float b2v = __shfl_xor(av, 2);
          float b3v = __shfl_xor(b1v, 2);
          auto pick = [&](int k2) { return k2 == 0 ? av : (k2 == 1 ? b1v : (k2 == 2 ? b2v : b3v)); };
          float iv = pick(gq), fv = pick(gq ^ 1), gv = pick(gq ^ 2), ov = pick(gq ^ 3);
          float cc = fv * creg[c][ntp][r] + iv * gv;
          creg[c][ntp][r] = cc;
          float h = ov * tanh_f(cc);
          if (gq == 0) {
            int s_ = c * 16 + khalf * 4 + r;
            hstage[s_ * 32 + ul] = (half_t)h;
            if (hlast != nullptr && t == T_ - 1)
              hlast[(size_t)(seqRow0 + s_) * H_ + u0 + ul] = h;
          }
        }
      }
    }
    __syncthreads();

    waitvm0();
    {
      uint2v val = *reinterpret_cast<const uint2v*>(&hstage[srow * 32 + spart * 4]);
      store8_cc(ring + ((size_t)(sc_ * 8 + member) * rr + ringRow0 + srow) * 32 + spart * 4, val);
      if (hseq)
        store8_cc(&hseq[((size_t)(seqRow0 + srow) * T_ + t) * H_ + u0 + spart * 4], val);
    }
  }
}

__global__ __launch_bounds__(256, 1) void lstm_p1(
    const half_t* __restrict__ W0, const half_t* __restrict__ W1,
    const float* __restrict__ b0, const float* __restrict__ b1,
    const half_t* __restrict__ xseq, half_t* __restrict__ ring,
    float* __restrict__ hl0, float* __restrict__ hl1) {
  __shared__ __align__(8) half_t hstage[32 * 32];
  const int member = blockIdx.x >> 5;
  const int g = blockIdx.x & 31;
  const int run = g >> 4;
  run_layer<11, false>(run ? W1 : W0, run ? b1 : b0, xseq,
                       ring, 1024, nullptr, run ? hl1 : hl0,
                       g * 32, g * 32 - run * 512, member * 32, member, hstage);
}

// ========== pipelined m-layer: flag-vector sync, 64-sample groups, 512 thr ==========
// group g = 64 sample rows; 8 members (32-unit gate slices). Weights in VGPRs
// (full 256-VGPR budget: 8 waves = 2/SIMD, NO launch_bounds min-wave cap).
// waves 0-3 process sample-chunks 0-1, waves 4-7 chunks 2-3 (w4 = wave&3).
// Sync: per-(layer,group) flag line (8 member counters, 128B); producer
// increments after drained publish; consumer polls 8 own flags (>=t) and, if
// POLLX, 8 upstream flags (>=t+1) -- retries cost 16 x 4B, not 16 KB.
template<int KT, bool POLLX>
__device__ __forceinline__ void ml_layer(
    const half_t* __restrict__ Wcat, const float* __restrict__ bias,
    const half_t* __restrict__ xseq,
    half_t* __restrict__ ring,
    half_t* __restrict__ hseq, float* __restrict__ hlast,
    unsigned int* __restrict__ ownf, const unsigned int* __restrict__ upf,
    int seqRow0, int u0, int member,
    half_t* hstage) {
  constexpr int XKT = KT - 8;
  constexpr int XK = XKT * 32;
  constexpr int Kc = KT * 32;
  const int tid = threadIdx.x, lane = tid & 63, wave = tid >> 6;
  const int w4 = wave & 3, chalf = wave >> 2;
  const int col = lane & 15, khalf = lane >> 4, klo8 = khalf * 8, gq = col & 3;
  const int srow = tid >> 3, spart = tid & 7;   // 512 thr: 64 rows x 8 parts

  half8 wreg[2][KT];
  float brg[2];
#pragma unroll
  for (int ntp = 0; ntp < 2; ++ntp) {
    int lrow = (w4 * 2 + ntp) * 16 + col;
    int grow = (lrow & 3) * 256 + u0 + (lrow >> 2);
#pragma unroll
    for (int kt = 0; kt < KT; ++kt)
      wreg[ntp][kt] = *reinterpret_cast<const half8*>(Wcat + (size_t)grow * Kc + kt * 32 + klo8);
    brg[ntp] = bias[grow];
  }

  const half_t* xrow[2];
#pragma unroll
  for (int c = 0; c < 2; ++c)
    xrow[c] = xseq + (size_t)(seqRow0 + (chalf * 2 + c) * 16 + col) * T_ * XK + klo8;

  float creg[2][2][4] = {};

#pragma unroll 1
  for (int t = 0; t < T_; ++t) {
    const bool hasH = (t > 0);

    // ---- cheap flag poll: wave 0, lanes 0-7 own ring, 8-15 upstream ----
    if (wave == 0) {
      const unsigned tgt = (lane < 8) ? (unsigned)t : (unsigned)(t + 1);
      const unsigned int* fp = (lane < 8) ? (ownf + lane) : (upf + (lane - 8));
      const bool act = (lane < 8) ? (t > 0) : (POLLX && lane < 16);
      int guard = 0;
      for (;;) {
        unsigned f = 0xFFFFFFFFu;
        if (act) f = __hip_atomic_load(fp, __ATOMIC_RELAXED, __HIP_MEMORY_SCOPE_AGENT);
        if (__all(f >= tgt)) break;
        if (++guard > (1 << 22)) break;   // bounded failure, no hang
        __builtin_amdgcn_s_sleep(2);
      }
    }
    __syncthreads();                       // also orders prev publish-read vs hstage overwrite
    __builtin_amdgcn_sched_barrier(0);

    // ---- 2 chunks per wave-half: issue -> wait -> compute (bounds VGPRs) ----
#pragma unroll
    for (int c = 0; c < 2; ++c) {
      const int cc = chalf * 2 + c;
      half8 ah[8];
      half8 ax[XKT];
      if (hasH) {
#pragma unroll
        for (int kt = 0; kt < 8; ++kt)
          ah[kt] = gload16_cc(
              ring + ((size_t)(((t - 1) & 1) * 8 + kt) * 512 + seqRow0 + cc * 16 + col) * 32 + klo8);
      }
      if (POLLX) {
#pragma unroll
        for (int kx = 0; kx < XKT; ++kx)
          ax[kx] = gload16_cc(xrow[c] + (size_t)t * XK + kx * 32);
      } else {
#pragma unroll
        for (int kx = 0; kx < XKT; ++kx)
          ax[kx] = *reinterpret_cast<const half8*>(xrow[c] + (size_t)t * XK + kx * 32);
      }
      waitvm0();

      f32x4 acc[2];
      acc[0] = (f32x4){brg[0], brg[0], brg[0], brg[0]};
      acc[1] = (f32x4){brg[1], brg[1], brg[1], brg[1]};
      if (hasH) {
#pragma unroll
        for (int kt = 0; kt < 8; ++kt) {
          acc[0] = __builtin_amdgcn_mfma_f32_16x16x32_f16(ah[kt], wreg[0][kt], acc[0], 0, 0, 0);
          acc[1] = __builtin_amdgcn_mfma_f32_16x16x32_f16(ah[kt], wreg[1][kt], acc[1], 0, 0, 0);
        }
      }
#pragma unroll
      for (int kx = 0; kx < XKT; ++kx) {
        acc[0] = __builtin_amdgcn_mfma_f32_16x16x32_f16(ax[kx], wreg[0][8 + kx], acc[0], 0, 0, 0);
        acc[1] = __builtin_amdgcn_mfma_f32_16x16x32_f16(ax[kx], wreg[1][8 + kx], acc[1], 0, 0, 0);
      }
#pragma unroll
      for (int ntp = 0; ntp < 2; ++ntp) {
        int nt = w4 * 2 + ntp;
        int ul = nt * 4 + (col >> 2);
#pragma unroll
        for (int r = 0; r < 4; ++r) {
          float v = acc[ntp][r];
          float y = (gq == 2) ? 2.0f * v : v;
          float s = 1.0f / (1.0f + __expf(-y));
          float av = (gq == 2) ? (2.0f * s - 1.0f) : s;
          float b1v = __shfl_xor(av, 1);
          float b2v = __shfl_xor(av, 2);
          float b3v = __shfl_xor(b1v, 2);
          auto pick = [&](int k2) { return k2 == 0 ? av : (k2 == 1 ? b1v : (k2 == 2 ? b2v : b3v)); };
          float iv = pick(gq), fv = pick(gq ^ 1), gv = pick(gq ^ 2), ov = pick(gq ^ 3);
          float ccv = fv * creg[c][ntp][r] + iv * gv;
          creg[c][ntp][r] = ccv;
          float h = ov * tanh_f(ccv);
          if (gq == 0) {
            int s_ = cc * 16 + khalf * 4 + r;
            hstage[s_ * 32 + ul] = (half_t)h;
            if (hlast != nullptr && t == T_ - 1)
              hlast[(size_t)(seqRow0 + s_) * H_ + u0 + ul] = h;
          }
        }
      }
    }
    __syncthreads();

    // ---- publish: ring (parity slot) + hseq; drain; flag increment ----
    {
      uint2v val = *reinterpret_cast<const uint2v*>(&hstage[srow * 32 + spart * 4]);
      store8_cc(ring + ((size_t)((t & 1) * 8 + member) * 512 + seqRow0 + srow) * 32 + spart * 4, val);
      if (hseq)
        store8_cc(&hseq[((size_t)(seqRow0 + srow) * T_ + t) * H_ + u0 + spart * 4], val);
    }
    waitvm0();
    __syncthreads();
    if (tid == 0)
      __hip_atomic_fetch_add(ownf + member, 1u, __ATOMIC_RELAXED, __HIP_MEMORY_SCOPE_AGENT);
  }
}

__global__ __launch_bounds__(512, 1) void lstm_ml512(
    const half_t* __restrict__ Wm0, const float* __restrict__ Bm0,
    const half_t* __restrict__ Wm1, const float* __restrict__ Bm1,
    const half_t* __restrict__ Wm2, const float* __restrict__ Bm2,
    const half_t* __restrict__ seqb, half_t* __restrict__ hs0, half_t* __restrict__ hs1,
    half_t* __restrict__ ring0, half_t* __restrict__ ring1, half_t* __restrict__ ring2,
    unsigned int* __restrict__ flags, float* __restrict__ hlast2) {
  __shared__ __align__(8) half_t hstage[64 * 32];
  const int L = blockIdx.x / 64;
  const int r = blockIdx.x % 64;
  const int member = r >> 3;
  const int g = r & 7;
  const int seqRow0 = g * 64, u0 = member * 32;
  unsigned int* ownf = flags + (L * 8 + g) * 32;
  const unsigned int* upf = (L > 0) ? (flags + ((L - 1) * 8 + g) * 32) : flags;
  if (L == 0)
    ml_layer<11, false>(Wm0, Bm0, seqb, ring0, hs0, nullptr, ownf, upf, seqRow0, u0, member, hstage);
  else if (L == 1)
    ml_layer<16, true>(Wm1, Bm1, hs0, ring1, hs1, nullptr, ownf, upf, seqRow0, u0, member, hstage);
  else
    ml_layer<16, true>(Wm2, Bm2, hs1, ring2, nullptr, hlast2, ownf, upf, seqRow0, u0, member, hstage);
}

// ---------- angles/trans FC + rotation matrices ----------
__global__ void fc3_rot(const float* __restrict__ hrot, const float* __restrict__ htr,
                        const float* __restrict__ rfcW, const float* __restrict__ rfcb,
                        const float* __restrict__ tfcW, const float* __restrict__ tfcb,
                        float* __restrict__ rt) {
  int idx = blockIdx.x * blockDim.x + threadIdx.x;
  if (idx >= 2 * N_) return;
  const float* h1 = hrot + (size_t)idx * H_;
  const float* h2 = htr + (size_t)idx * H_;
  float ang[3], tr[3];
#pragma unroll
  for (int i = 0; i < 3; ++i) {
    float a = rfcb[i], b = tfcb[i];
    for (int j = 0; j < H_; ++j) { a += h1[j] * rfcW[i * H_ + j]; b += h2[j] * tfcW[i * H_ + j]; }
    ang[i] = a * 3.14159265358979323846f;
    tr[i] = b;
  }
  float c0 = cosf(ang[0]), s0 = sinf(ang[0]);
  float c1 = cosf(ang[1]), s1 = sinf(ang[1]);
  float c2 = cosf(ang[2]), s2 = sinf(ang[2]);
  float Rx[3][3] = {{1, 0, 0}, {0, c0, s0}, {0, -s0, c0}};
  float Ry[3][3] = {{c1, 0, -s1}, {0, 1, 0}, {s1, 0, c1}};
  float Rz[3][3] = {{c2, s2, 0}, {-s2, c2, 0}, {0, 0, 1}};
  float A[3][3], R[3][3];
  for (int i = 0; i < 3; ++i)
    for (int j = 0; j < 3; ++j) {
      float s = 0;
      for (int k = 0; k < 3; ++k) s += Rx[i][k] * Ry[k][j];
      A[i][j] = s;
    }
  for (int i = 0; i < 3; ++i)
    for (int j = 0; j < 3; ++j) {
      float s = 0;
      for (int k = 0; k < 3; ++k) s += A[i][k] * Rz[k][j];
      R[i][j] = s;
    }
  float* o = rt + (size_t)idx * 12;
  for (int i = 0; i < 9; ++i) o[i] = R[i / 3][i % 3];
  for (int i = 0; i < 3; ++i) o[9 + i] = tr[i];
}

// ---------- seq2 = R @ (x - trans), overwrites seqb ----------
__global__ void transform_seq(const float* __restrict__ x, const float* __restrict__ rt,
                              half_t* __restrict__ seqb) {
  int idx = blockIdx.x * 256 + threadIdx.x;
  const int tot = 2 * N_ * T_ * V_;
  if (idx >= tot) return;
  int v = idx % V_; int r = idx / V_;
  int t = r % T_; int r2 = r / T_;
  int n = r2 % N_; int p = r2 / N_;
  const float* o = rt + ((size_t)p * N_ + n) * 12;
  float xv[3];
#pragma unroll
  for (int c = 0; c < 3; ++c)
    xv[c] = x[(((size_t)n * C_ + c) * T_ + t) * (V_ * 2) + v * 2 + p] - o[9 + c];
  size_t base = (((size_t)p * N_ + n) * T_ + t) * XP1_;
#pragma unroll
  for (int i = 0; i < 3; ++i) {
    float s = o[i * 3 + 0] * xv[0] + o[i * 3 + 1] * xv[1] + o[i * 3 + 2] * xv[2];
    seqb[base + i * V_ + v] = (half_t)s;
  }
}

// ---------- maxpool over persons + final FC ----------
__global__ void final_fc(const float* __restrict__ hM2, const float* __restrict__ fcW,
                         const float* __restrict__ fcb, float* __restrict__ out) {
  int n = blockIdx.x;
  __shared__ float hm[H_];
  for (int j = threadIdx.x; j < H_; j += blockDim.x)
    hm[j] = fmaxf(hM2[(size_t)n * H_ + j], hM2[(size_t)(N_ + n) * H_ + j]);
  __syncthreads();
  if (threadIdx.x < NCLS_) {
    float acc = fcb[threadIdx.x];
    for (int j = 0; j < H_; ++j) acc += hm[j] * fcW[threadIdx.x * H_ + j];
    out[n * NCLS_ + threadIdx.x] = acc;
  }
}

extern "C" void kernel_launch(void* const* d_in, const int* in_sizes, int n_in,
                              void* d_out, int out_size, void* d_ws, size_t ws_size,
                              hipStream_t stream) {
  const float* x       = (const float*)d_in[0];
  const float* rot_Wih = (const float*)d_in[1];
  const float* rot_Whh = (const float*)d_in[2];
  const float* rot_bih = (const float*)d_in[3];
  const float* rot_bhh = (const float*)d_in[4];
  const float* rot_fcW = (const float*)d_in[5];
  const float* rot_fcb = (const float*)d_in[6];
  const float* tr_Wih  = (const float*)d_in[7];
  const float* tr_Whh  = (const float*)d_in[8];
  const float* tr_bih  = (const float*)d_in[9];
  const float* tr_bhh  = (const float*)d_in[10];
  const float* tr_fcW  = (const float*)d_in[11];
  const float* tr_fcb  = (const float*)d_in[12];
  const float* m0_Wih  = (const float*)d_in[13];
  const float* m0_Whh  = (const float*)d_in[14];
  const float* m0_bih  = (const float*)d_in[15];
  const float* m0_bhh  = (const float*)d_in[16];
  const float* m1_Wih  = (const float*)d_in[17];
  const float* m1_Whh  = (const float*)d_in[18];
  const float* m1_bih  = (const float*)d_in[19];
  const float* m1_bhh  = (const float*)d_in[20];
  const float* m2_Wih  = (const float*)d_in[21];
  const float* m2_Whh  = (const float*)d_in[22];
  const float* m2_bih  = (const float*)d_in[23];
  const float* m2_bhh  = (const float*)d_in[24];
  const float* fcW     = (const float*)d_in[25];
  const float* fcb     = (const float*)d_in[26];

  char* ws = (char*)d_ws;
  size_t off = 0;
  auto take = [&](size_t b) -> void* {
    void* pp = ws + off;
    off = (off + b + 255) & ~(size_t)255;
    return pp;
  };
  half_t* WC_ROT = (half_t*)take((size_t)G4_ * 352 * 2);
  half_t* WC_TR  = (half_t*)take((size_t)G4_ * 352 * 2);
  half_t* WC_M0  = (half_t*)take((size_t)G4_ * 352 * 2);
  half_t* WC_M1  = (half_t*)take((size_t)G4_ * 512 * 2);
  half_t* WC_M2  = (half_t*)take((size_t)G4_ * 512 * 2);
  float* B_ROT = (float*)take((size_t)G4_ * 4);
  float* B_TR  = (float*)take((size_t)G4_ * 4);
  float* B_M0  = (float*)take((size_t)G4_ * 4);
  float* B_M1  = (float*)take((size_t)G4_ * 4);
  float* B_M2  = (float*)take((size_t)G4_ * 4);
  half_t* SEQB = (half_t*)take((size_t)2 * N_ * T_ * XP1_ * 2);
  float* HL_ROT = (float*)take((size_t)2 * N_ * H_ * 4);
  float* HL_TR  = (float*)take((size_t)2 * N_ * H_ * 4);
  float* HL_M2  = (float*)take((size_t)2 * N_ * H_ * 4);
  float* RT     = (float*)take((size_t)2 * N_ * 12 * 4);
  half_t* RINGP  = (half_t*)take((size_t)3 * 8 * 1024 * 32 * 2);
  half_t* RINGM0 = (half_t*)take((size_t)2 * 8 * 512 * 32 * 2);
  half_t* RINGM1 = (half_t*)take((size_t)2 * 8 * 512 * 32 * 2);
  half_t* RINGM2 = (half_t*)take((size_t)2 * 8 * 512 * 32 * 2);
  unsigned int* FLAGS = (unsigned int*)take((size_t)24 * 32 * sizeof(unsigned int));
  half_t* HS0 = (half_t*)take((size_t)2 * N_ * T_ * H_ * 2);
  half_t* HS1 = (half_t*)take((size_t)2 * N_ * T_ * H_ * 2);

  // p1 sentinel ring pre-fill; ml flags zeroed (flag protocol, no sentinels)
  hipMemsetAsync(RINGP, 0xFF, (size_t)3 * 8 * 1024 * 32 * 2, stream);
  hipMemsetAsync(FLAGS, 0, (size_t)24 * 32 * sizeof(unsigned int), stream);

  // ---- pack weights (fp16) + fused biases ----
  pack_wcat<<<1408, 256, 0, stream>>>(rot_Whh, rot_Wih, rot_bih, rot_bhh, WC_ROT, B_ROT, IN_, 352);
  pack_wcat<<<1408, 256, 0, stream>>>(tr_Whh, tr_Wih, tr_bih, tr_bhh, WC_TR, B_TR, IN_, 352);
  pack_wcat<<<1408, 256, 0, stream>>>(m0_Whh, m0_Wih, m0_bih, m0_bhh, WC_M0, B_M0, IN_, 352);
  pack_wcat<<<2048, 256, 0, stream>>>(m1_Whh, m1_Wih, m1_bih, m1_bhh, WC_M1, B_M1, H_, 512);
  pack_wcat<<<2048, 256, 0, stream>>>(m2_Whh, m2_Wih, m2_bih, m2_bhh, WC_M2, B_M2, H_, 512);

  pack_seq<<<(2 * N_ * T_ * XP1_ + 255) / 256, 256, 0, stream>>>(x, SEQB);

  // ---- phase 1: rot & tr (proven sentinel protocol) ----
  lstm_p1<<<256, 256, 0, stream>>>(WC_ROT, WC_TR, B_ROT, B_TR, SEQB, RINGP, HL_ROT, HL_TR);

  fc3_rot<<<2, 256, 0, stream>>>(HL_ROT, HL_TR, rot_fcW, rot_fcb, tr_fcW, tr_fcb, RT);
  transform_seq<<<(2 * N_ * T_ * V_ + 255) / 256, 256, 0, stream>>>(x, RT, SEQB);

  // ---- fused m0/m1/m2 wavefront pipeline: 192 x 512-thread blocks,
  //      all co-resident at 1 block/CU, full VGPR budget (weights stay in regs)
  lstm_ml512<<<192, 512, 0, stream>>>(
      WC_M0, B_M0, WC_M1, B_M1, WC_M2, B_M2,
      SEQB, HS0, HS1, RINGM0, RINGM1, RINGM2, FLAGS, HL_M2);

  final_fc<<<256, 64, 0, stream>>>(HL_M2, fcW, fcb, (float*)d_out);
}

// Round 13
// 6374.585 us; speedup vs baseline: 3.7552x; 1.0670x over previous
//
#include <hip/hip_runtime.h>
#include <hip/hip_fp16.h>

#define N_ 256
#define C_ 3
#define T_ 300
#define V_ 25
#define H_ 256
#define G4_ 1024   // 4*H
#define IN_ 75
#define XP1_ 96    // padded input-K
#define NCLS_ 60

typedef _Float16 half_t;
typedef __attribute__((ext_vector_type(8))) _Float16 half8;
typedef __attribute__((ext_vector_type(4))) float f32x4;
typedef __attribute__((ext_vector_type(4))) unsigned int uint4v;
typedef __attribute__((ext_vector_type(2))) unsigned int uint2v;

static_assert(sizeof(half8) == 16, "half8 must be 16B");

__device__ __forceinline__ float tanh_f(float x) {
  x = fminf(fmaxf(x, -15.0f), 15.0f);
  float e = __expf(2.0f * x);
  return (e - 1.0f) / (e + 1.0f);
}

// ---- MALL-coherent ops (PROVEN rounds 3/5/6/10/11): bypass non-coherent L1/L2 ----
__device__ __forceinline__ half8 gload16_cc(const void* p) {
  uint4v r;
  asm volatile("global_load_dwordx4 %0, %1, off sc0 sc1" : "=v"(r) : "v"(p));
  return __builtin_bit_cast(half8, r);
}
__device__ __forceinline__ void store8_cc(void* p, uint2v v) {
  asm volatile("global_store_dwordx2 %0, %1, off sc0 sc1" :: "v"(p), "v"(v) : "memory");
}
__device__ __forceinline__ void waitvm0() {
  asm volatile("s_waitcnt vmcnt(0)" ::: "memory");
  __builtin_amdgcn_sched_barrier(0);
}

// ---------- pack [Whh | Wih | 0pad] rows into fp16, bias = bih+bhh ----------
__global__ void pack_wcat(const float* __restrict__ Whh, const float* __restrict__ Wih,
                          const float* __restrict__ bih, const float* __restrict__ bhh,
                          half_t* __restrict__ dstW, float* __restrict__ dstB,
                          int inDim, int Kc) {
  int idx = blockIdx.x * 256 + threadIdx.x;
  int tot = G4_ * Kc;
  if (idx < tot) {
    int row = idx / Kc, k = idx % Kc;
    float v = 0.0f;
    if (k < H_) v = Whh[row * H_ + k];
    else if (k - H_ < inDim) v = Wih[row * inDim + (k - H_)];
    dstW[idx] = (half_t)v;
  }
  if (idx < G4_) dstB[idx] = bih[idx] + bhh[idx];
}

// ---------- pack x -> seqb[p][n][t][96] fp16 ----------
__global__ void pack_seq(const float* __restrict__ x, half_t* __restrict__ seqb) {
  int idx = blockIdx.x * 256 + threadIdx.x;
  const int tot = 2 * N_ * T_ * XP1_;
  if (idx >= tot) return;
  int k = idx % XP1_; int r = idx / XP1_;
  int t = r % T_; int r2 = r / T_;
  int n = r2 % N_; int p = r2 / N_;
  float v = 0.0f;
  if (k < IN_) {
    int c = k / V_, vv = k % V_;
    v = x[(((size_t)n * C_ + c) * T_ + t) * (V_ * 2) + vv * 2 + p];
  }
  seqb[idx] = (half_t)v;
}

// ========== phase-1 layer (UNCHANGED, proven rounds 10/11): sentinel poll ==========
template<int KT, bool POLLX>
__device__ __forceinline__ void run_layer(
    const half_t* __restrict__ Wcat, const float* __restrict__ bias,
    const half_t* __restrict__ xseq,
    half_t* __restrict__ ring, int rr,
    half_t* __restrict__ hseq, float* __restrict__ hlast,
    int ringRow0, int seqRow0, int u0, int member,
    half_t* hstage) {
  constexpr int XKT = KT - 8;
  constexpr int XK = XKT * 32;
  constexpr int Kc = KT * 32;
  const int tid = threadIdx.x, lane = tid & 63, wave = tid >> 6;
  const int col = lane & 15, khalf = lane >> 4, klo8 = khalf * 8, gq = col & 3;
  const int srow = tid >> 3, spart = tid & 7;

  half8 wreg[2][KT];
  float brg[2];
#pragma unroll
  for (int ntp = 0; ntp < 2; ++ntp) {
    int lrow = (wave * 2 + ntp) * 16 + col;
    int grow = (lrow & 3) * 256 + u0 + (lrow >> 2);
#pragma unroll
    for (int kt = 0; kt < KT; ++kt)
      wreg[ntp][kt] = *reinterpret_cast<const half8*>(Wcat + (size_t)grow * Kc + kt * 32 + klo8);
    brg[ntp] = bias[grow];
  }

  const half_t* xrow[2];
#pragma unroll
  for (int c = 0; c < 2; ++c)
    xrow[c] = xseq + (size_t)(seqRow0 + c * 16 + col) * T_ * XK + klo8;

  float creg[2][2][4] = {};

  auto chk = [](half8 v) -> unsigned {
    uint4v u = __builtin_bit_cast(uint4v, v);
    return ((u[0] & 0xFFFFu) == 0xFFFFu) | ((u[1] & 0xFFFFu) == 0xFFFFu) |
           ((u[2] & 0xFFFFu) == 0xFFFFu) | ((u[3] & 0xFFFFu) == 0xFFFFu);
  };

#pragma unroll 1
  for (int t = 0; t < T_; ++t) {
    const int sc_ = t % 3;
    const int sp_ = (t + 2) % 3;
    const int sn_ = (t + 1) % 3;
    const bool hasH = (t > 0);

    half8 ax[2][XKT];
    half8 ah[2][8];

    if (!POLLX) {
#pragma unroll
      for (int c = 0; c < 2; ++c)
#pragma unroll
        for (int kx = 0; kx < XKT; ++kx)
          ax[c][kx] = *reinterpret_cast<const half8*>(xrow[c] + (size_t)t * XK + kx * 32);
    }

    if (hasH || POLLX) {
      int guard = 0;
      for (;;) {
        if (hasH) {
#pragma unroll
          for (int c = 0; c < 2; ++c)
#pragma unroll
            for (int kt = 0; kt < 8; ++kt)
              ah[c][kt] = gload16_cc(
                  ring + ((size_t)(sp_ * 8 + kt) * rr + ringRow0 + c * 16 + col) * 32 + klo8);
        }
        if (POLLX) {
#pragma unroll
          for (int c = 0; c < 2; ++c)
#pragma unroll
            for (int kx = 0; kx < XKT; ++kx)
              ax[c][kx] = gload16_cc(xrow[c] + (size_t)t * XK + kx * 32);
        }
        waitvm0();
        unsigned bad = 0;
        if (hasH) {
#pragma unroll
          for (int c = 0; c < 2; ++c)
#pragma unroll
            for (int kt = 0; kt < 8; ++kt) bad |= chk(ah[c][kt]);
        }
        if (POLLX) {
#pragma unroll
          for (int c = 0; c < 2; ++c)
#pragma unroll
            for (int kx = 0; kx < XKT; ++kx) bad |= chk(ax[c][kx]);
        }
        if (__all(bad == 0u)) break;
        if (++guard > (1 << 20)) break;
        __builtin_amdgcn_s_sleep(1);
      }
      __syncthreads();
      __builtin_amdgcn_sched_barrier(0);
    }

    {
      uint2v sent = {0xFFFFFFFFu, 0xFFFFFFFFu};
      store8_cc(ring + ((size_t)(sn_ * 8 + member) * rr + ringRow0 + srow) * 32 + spart * 4, sent);
    }

#pragma unroll
    for (int c = 0; c < 2; ++c) {
      f32x4 acc[2];
      acc[0] = (f32x4){brg[0], brg[0], brg[0], brg[0]};
      acc[1] = (f32x4){brg[1], brg[1], brg[1], brg[1]};
      if (hasH) {
#pragma unroll
        for (int kt = 0; kt < 8; ++kt) {
          acc[0] = __builtin_amdgcn_mfma_f32_16x16x32_f16(ah[c][kt], wreg[0][kt], acc[0], 0, 0, 0);
          acc[1] = __builtin_amdgcn_mfma_f32_16x16x32_f16(ah[c][kt], wreg[1][kt], acc[1], 0, 0, 0);
        }
      }
#pragma unroll
      for (int kx = 0; kx < XKT; ++kx) {
        acc[0] = __builtin_amdgcn_mfma_f32_16x16x32_f16(ax[c][kx], wreg[0][8 + kx], acc[0], 0, 0, 0);
        acc[1] = __builtin_amdgcn_mfma_f32_16x16x32_f16(ax[c][kx], wreg[1][8 + kx], acc[1], 0, 0, 0);
      }
#pragma unroll
      for (int ntp = 0; ntp < 2; ++ntp) {
        int nt = wave * 2 + ntp;
        int ul = nt * 4 + (col >> 2);
#pragma unroll
        for (int r = 0; r < 4; ++r) {
          float v = acc[ntp][r];
          float y = (gq == 2) ? 2.0f * v : v;
          float s = 1.0f / (1.0f + __expf(-y));
          float av = (gq == 2) ? (2.0f * s - 1.0f) : s;
          float b1v = __shfl_xor(av, 1);
          float b2v = __shfl_xor(av, 2);
          float b3v = __shfl_xor(b1v, 2);
          auto pick = [&](int k2) { return k2 == 0 ? av : (k2 == 1 ? b1v : (k2 == 2 ? b2v : b3v)); };
          float iv = pick(gq), fv = pick(gq ^ 1), gv = pick(gq ^ 2), ov = pick(gq ^ 3);
          float cc = fv * creg[c][ntp][r] + iv * gv;
          creg[c][ntp][r] = cc;
          float h = ov * tanh_f(cc);
          if (gq == 0) {
            int s_ = c * 16 + khalf * 4 + r;
            hstage[s_ * 32 + ul] = (half_t)h;
            if (hlast != nullptr && t == T_ - 1)
              hlast[(size_t)(seqRow0 + s_) * H_ + u0 + ul] = h;
          }
        }
      }
    }
    __syncthreads();

    waitvm0();
    {
      uint2v val = *reinterpret_cast<const uint2v*>(&hstage[srow * 32 + spart * 4]);
      store8_cc(ring + ((size_t)(sc_ * 8 + member) * rr + ringRow0 + srow) * 32 + spart * 4, val);
      if (hseq)
        store8_cc(&hseq[((size_t)(seqRow0 + srow) * T_ + t) * H_ + u0 + spart * 4], val);
    }
  }
}

__global__ __launch_bounds__(256, 1) void lstm_p1(
    const half_t* __restrict__ W0, const half_t* __restrict__ W1,
    const float* __restrict__ b0, const float* __restrict__ b1,
    const half_t* __restrict__ xseq, half_t* __restrict__ ring,
    float* __restrict__ hl0, float* __restrict__ hl1) {
  __shared__ __align__(8) half_t hstage[32 * 32];
  const int member = blockIdx.x >> 5;
  const int g = blockIdx.x & 31;
  const int run = g >> 4;
  run_layer<11, false>(run ? W1 : W0, run ? b1 : b0, xseq,
                       ring, 1024, nullptr, run ? hl1 : hl0,
                       g * 32, g * 32 - run * 512, member * 32, member, hstage);
}

// ========== pipelined m-layer: flag sync (round-11 proven protocol) +
//            LDS-staged operand panels (dedup 4x sc0sc1 loads) ==========
// group g = 64 sample rows; 8 members. ring [2][8][512][32].
// hseq layout for POLLX layers: [t][512][256] (contiguous per group-step).
// Stage: wave w loads member w's ring slice (coalesced 4KB) + x slice,
// writes LDS [row][256] with XOR swizzle byte^=(row&31)<<4; fragments via
// ds_read_b128 (~2-way conflicts = free).
template<int KT, bool POLLX>
__device__ __forceinline__ void ml_layer(
    const half_t* __restrict__ Wcat, const float* __restrict__ bias,
    const half_t* __restrict__ xseq,
    half_t* __restrict__ ring,
    half_t* __restrict__ hseq, float* __restrict__ hlast,
    unsigned int* __restrict__ ownf, const unsigned int* __restrict__ upf,
    int seqRow0, int u0, int member,
    half_t* hlds, half_t* xlds, half_t* hstage) {
  constexpr int XKT = KT - 8;
  constexpr int XK = XKT * 32;
  constexpr int Kc = KT * 32;
  const int tid = threadIdx.x, lane = tid & 63, wave = tid >> 6;
  const int w4 = wave & 3, chalf = wave >> 2;
  const int col = lane & 15, khalf = lane >> 4, klo8 = khalf * 8, gq = col & 3;
  const int srow = tid >> 3, spart = tid & 7;   // 512 thr: 64 rows x 8 parts

  half8 wreg[2][KT];
  float brg[2];
#pragma unroll
  for (int ntp = 0; ntp < 2; ++ntp) {
    int lrow = (w4 * 2 + ntp) * 16 + col;
    int grow = (lrow & 3) * 256 + u0 + (lrow >> 2);
#pragma unroll
    for (int kt = 0; kt < KT; ++kt)
      wreg[ntp][kt] = *reinterpret_cast<const half8*>(Wcat + (size_t)grow * Kc + kt * 32 + klo8);
    brg[ntp] = bias[grow];
  }

  const half_t* xrow[2];
  if (!POLLX) {
#pragma unroll
    for (int c = 0; c < 2; ++c)
      xrow[c] = xseq + (size_t)(seqRow0 + (chalf * 2 + c) * 16 + col) * T_ * XK + klo8;
  }

  float creg[2][2][4] = {};

#pragma unroll 1
  for (int t = 0; t < T_; ++t) {
    const bool hasH = (t > 0);

    // direct cached x loads for m0 (issued before the poll, overlap)
    half8 axd[2][XKT];
    if (!POLLX) {
#pragma unroll
      for (int c = 0; c < 2; ++c)
#pragma unroll
        for (int kx = 0; kx < XKT; ++kx)
          axd[c][kx] = *reinterpret_cast<const half8*>(xrow[c] + (size_t)t * XK + kx * 32);
    }

    // ---- flag poll (round-11 exact): wave0 lanes 0-7 own (>=t), 8-15 up (>=t+1) ----
    if (wave == 0) {
      const unsigned tgt = (lane < 8) ? (unsigned)t : (unsigned)(t + 1);
      const bool act = (lane < 8) ? (t > 0) : (POLLX && lane < 16);
      const unsigned int* fp = (lane < 8) ? (ownf + lane) : (upf + (lane - 8));
      int guard = 0;
      for (;;) {
        unsigned f = 0xFFFFFFFFu;
        if (act) f = __hip_atomic_load(fp, __ATOMIC_RELAXED, __HIP_MEMORY_SCOPE_AGENT);
        if (__all(f >= tgt)) break;
        if (++guard > (1 << 22)) break;   // bounded failure, no hang
        __builtin_amdgcn_s_sleep(2);
      }
    }
    __syncthreads();                       // orders prev publish-read vs hlds/hstage overwrite
    __builtin_amdgcn_sched_barrier(0);

    // ---- cooperative stage: wave w = member w's slice, row = lane ----
    {
      const int r = lane;
      half8 hv[4], xv[4];
      if (hasH) {
        const half_t* src = ring + ((size_t)(((t - 1) & 1) * 8 + wave) * 512 + seqRow0 + r) * 32;
#pragma unroll
        for (int j = 0; j < 4; ++j) hv[j] = gload16_cc(src + j * 8);
      }
      if (POLLX) {
        const half_t* sx = xseq + ((size_t)t * 512 + seqRow0 + r) * 256 + wave * 32;
#pragma unroll
        for (int j = 0; j < 4; ++j) xv[j] = gload16_cc(sx + j * 8);
      }
      waitvm0();
      if (hasH) {
#pragma unroll
        for (int j = 0; j < 4; ++j)
          *reinterpret_cast<half8*>(&hlds[r * 256 + 8 * ((wave * 4 + j) ^ (r & 31))]) = hv[j];
      }
      if (POLLX) {
#pragma unroll
        for (int j = 0; j < 4; ++j)
          *reinterpret_cast<half8*>(&xlds[r * 256 + 8 * ((wave * 4 + j) ^ (r & 31))]) = xv[j];
      }
    }
    __syncthreads();

    // ---- compute: 2 chunks per wave-half, fragments from LDS ----
#pragma unroll
    for (int c = 0; c < 2; ++c) {
      const int cc = chalf * 2 + c;
      const int row = cc * 16 + col;
      f32x4 acc[2];
      acc[0] = (f32x4){brg[0], brg[0], brg[0], brg[0]};
      acc[1] = (f32x4){brg[1], brg[1], brg[1], brg[1]};
      if (hasH) {
#pragma unroll
        for (int kt = 0; kt < 8; ++kt) {
          half8 ah = *reinterpret_cast<const half8*>(
              &hlds[row * 256 + 8 * ((kt * 4 + khalf) ^ (row & 31))]);
          acc[0] = __builtin_amdgcn_mfma_f32_16x16x32_f16(ah, wreg[0][kt], acc[0], 0, 0, 0);
          acc[1] = __builtin_amdgcn_mfma_f32_16x16x32_f16(ah, wreg[1][kt], acc[1], 0, 0, 0);
        }
      }
#pragma unroll
      for (int kx = 0; kx < XKT; ++kx) {
        half8 ax;
        if (POLLX)
          ax = *reinterpret_cast<const half8*>(
              &xlds[row * 256 + 8 * ((kx * 4 + khalf) ^ (row & 31))]);
        else
          ax = axd[c][kx];
        acc[0] = __builtin_amdgcn_mfma_f32_16x16x32_f16(ax, wreg[0][8 + kx], acc[0], 0, 0, 0);
        acc[1] = __builtin_amdgcn_mfma_f32_16x16x32_f16(ax, wreg[1][8 + kx], acc[1], 0, 0, 0);
      }
#pragma unroll
      for (int ntp = 0; ntp < 2; ++ntp) {
        int nt = w4 * 2 + ntp;
        int ul = nt * 4 + (col >> 2);
#pragma unroll
        for (int r = 0; r < 4; ++r) {
          float v = acc[ntp][r];
          float y = (gq == 2) ? 2.0f * v : v;
          float s = 1.0f / (1.0f + __expf(-y));
          float av = (gq == 2) ? (2.0f * s - 1.0f) : s;
          float b1v = __shfl_xor(av, 1);
          float b2v = __shfl_xor(av, 2);
          float b3v = __shfl_xor(b1v, 2);
          auto pick = [&](int k2) { return k2 == 0 ? av : (k2 == 1 ? b1v : (k2 == 2 ? b2v : b3v)); };
          float iv = pick(gq), fv = pick(gq ^ 1), gv = pick(gq ^ 2), ov = pick(gq ^ 3);
          float ccv = fv * creg[c][ntp][r] + iv * gv;
          creg[c][ntp][r] = ccv;
          float h = ov * tanh_f(ccv);
          if (gq == 0) {
            int s_ = cc * 16 + khalf * 4 + r;
            hstage[s_ * 32 + ul] = (half_t)h;
            if (hlast != nullptr && t == T_ - 1)
              hlast[(size_t)(seqRow0 + s_) * H_ + u0 + ul] = h;
          }
        }
      }
    }
    __syncthreads();

    // ---- publish: ring (parity) + hseq[t-major]; drain; flag (round-11 exact) ----
    {
      uint2v val = *reinterpret_cast<const uint2v*>(&hstage[srow * 32 + spart * 4]);
      store8_cc(ring + ((size_t)((t & 1) * 8 + member) * 512 + seqRow0 + srow) * 32 + spart * 4, val);
      if (hseq)
        store8_cc(&hseq[((size_t)t * 512 + seqRow0 + srow) * 256 + u0 + spart * 4], val);
    }
    waitvm0();
    __syncthreads();
    if (tid == 0)
      __hip_atomic_fetch_add(ownf + member, 1u, __ATOMIC_RELAXED, __HIP_MEMORY_SCOPE_AGENT);
  }
}

__global__ __launch_bounds__(512, 2) void lstm_ml512(
    const half_t* __restrict__ Wm0, const float* __restrict__ Bm0,
    const half_t* __restrict__ Wm1, const float* __restrict__ Bm1,
    const half_t* __restrict__ Wm2, const float* __restrict__ Bm2,
    const half_t* __restrict__ seqb, half_t* __restrict__ hs0, half_t* __restrict__ hs1,
    half_t* __restrict__ ring0, half_t* __restrict__ ring1, half_t* __restrict__ ring2,
    unsigned int* __restrict__ flags, float* __restrict__ hlast2) {
  __shared__ __align__(16) half_t hlds[64 * 256];   // 32 KB staged h panel
  __shared__ __align__(16) half_t xlds[64 * 256];   // 32 KB staged x panel (POLLX)
  __shared__ __align__(8)  half_t hstage[64 * 32];
  const int L = blockIdx.x / 64;
  const int r = blockIdx.x % 64;
  const int member = r >> 3;
  const int g = r & 7;
  const int seqRow0 = g * 64, u0 = member * 32;
  unsigned int* ownf = flags + (L * 8 + g) * 32;
  const unsigned int* upf = (L > 0) ? (flags + ((L - 1) * 8 + g) * 32) : flags;
  if (L == 0)
    ml_layer<11, false>(Wm0, Bm0, seqb, ring0, hs0, nullptr, ownf, upf, seqRow0, u0, member,
                        hlds, xlds, hstage);
  else if (L == 1)
    ml_layer<16, true>(Wm1, Bm1, hs0, ring1, hs1, nullptr, ownf, upf, seqRow0, u0, member,
                       hlds, xlds, hstage);
  else
    ml_layer<16, true>(Wm2, Bm2, hs1, ring2, nullptr, hlast2, ownf, upf, seqRow0, u0, member,
                       hlds, xlds, hstage);
}

// ---------- angles/trans FC + rotation matrices ----------
__global__ void fc3_rot(const float* __restrict__ hrot, const float* __restrict__ htr,
                        const float* __restrict__ rfcW, const float* __restrict__ rfcb,
                        const float* __restrict__ tfcW, const float* __restrict__ tfcb,
                        float* __restrict__ rt) {
  int idx = blockIdx.x * blockDim.x + threadIdx.x;
  if (idx >= 2 * N_) return;
  const float* h1 = hrot + (size_t)idx * H_;
  const float* h2 = htr + (size_t)idx * H_;
  float ang[3], tr[3];
#pragma unroll
  for (int i = 0; i < 3; ++i) {
    float a = rfcb[i], b = tfcb[i];
    for (int j = 0; j < H_; ++j) { a += h1[j] * rfcW[i * H_ + j]; b += h2[j] * tfcW[i * H_ + j]; }
    ang[i] = a * 3.14159265358979323846f;
    tr[i] = b;
  }
  float c0 = cosf(ang[0]), s0 = sinf(ang[0]);
  float c1 = cosf(ang[1]), s1 = sinf(ang[1]);
  float c2 = cosf(ang[2]), s2 = sinf(ang[2]);
  float Rx[3][3] = {{1, 0, 0}, {0, c0, s0}, {0, -s0, c0}};
  float Ry[3][3] = {{c1, 0, -s1}, {0, 1, 0}, {s1, 0, c1}};
  float Rz[3][3] = {{c2, s2, 0}, {-s2, c2, 0}, {0, 0, 1}};
  float A[3][3], R[3][3];
  for (int i = 0; i < 3; ++i)
    for (int j = 0; j < 3; ++j) {
      float s = 0;
      for (int k = 0; k < 3; ++k) s += Rx[i][k] * Ry[k][j];
      A[i][j] = s;
    }
  for (int i = 0; i < 3; ++i)
    for (int j = 0; j < 3; ++j) {
      float s = 0;
      for (int k = 0; k < 3; ++k) s += A[i][k] * Rz[k][j];
      R[i][j] = s;
    }
  float* o = rt + (size_t)idx * 12;
  for (int i = 0; i < 9; ++i) o[i] = R[i / 3][i % 3];
  for (int i = 0; i < 3; ++i) o[9 + i] = tr[i];
}

// ---------- seq2 = R @ (x - trans), overwrites seqb ----------
__global__ void transform_seq(const float* __restrict__ x, const float* __restrict__ rt,
                              half_t* __restrict__ seqb) {
  int idx = blockIdx.x * 256 + threadIdx.x;
  const int tot = 2 * N_ * T_ * V_;
  if (idx >= tot) return;
  int v = idx % V_; int r = idx / V_;
  int t = r % T_; int r2 = r / T_;
  int n = r2 % N_; int p = r2 / N_;
  const float* o = rt + ((size_t)p * N_ + n) * 12;
  float xv[3];
#pragma unroll
  for (int c = 0; c < 3; ++c)
    xv[c] = x[(((size_t)n * C_ + c) * T_ + t) * (V_ * 2) + v * 2 + p] - o[9 + c];
  size_t base = (((size_t)p * N_ + n) * T_ + t) * XP1_;
#pragma unroll
  for (int i = 0; i < 3; ++i) {
    float s = o[i * 3 + 0] * xv[0] + o[i * 3 + 1] * xv[1] + o[i * 3 + 2] * xv[2];
    seqb[base + i * V_ + v] = (half_t)s;
  }
}

// ---------- maxpool over persons + final FC ----------
__global__ void final_fc(const float* __restrict__ hM2, const float* __restrict__ fcW,
                         const float* __restrict__ fcb, float* __restrict__ out) {
  int n = blockIdx.x;
  __shared__ float hm[H_];
  for (int j = threadIdx.x; j < H_; j += blockDim.x)
    hm[j] = fmaxf(hM2[(size_t)n * H_ + j], hM2[(size_t)(N_ + n) * H_ + j]);
  __syncthreads();
  if (threadIdx.x < NCLS_) {
    float acc = fcb[threadIdx.x];
    for (int j = 0; j < H_; ++j) acc += hm[j] * fcW[threadIdx.x * H_ + j];
    out[n * NCLS_ + threadIdx.x] = acc;
  }
}

extern "C" void kernel_launch(void* const* d_in, const int* in_sizes, int n_in,
                              void* d_out, int out_size, void* d_ws, size_t ws_size,
                              hipStream_t stream) {
  const float* x       = (const float*)d_in[0];
  const float* rot_Wih = (const float*)d_in[1];
  const float* rot_Whh = (const float*)d_in[2];
  const float* rot_bih = (const float*)d_in[3];
  const float* rot_bhh = (const float*)d_in[4];
  const float* rot_fcW = (const float*)d_in[5];
  const float* rot_fcb = (const float*)d_in[6];
  const float* tr_Wih  = (const float*)d_in[7];
  const float* tr_Whh  = (const float*)d_in[8];
  const float* tr_bih  = (const float*)d_in[9];
  const float* tr_bhh  = (const float*)d_in[10];
  const float* tr_fcW  = (const float*)d_in[11];
  const float* tr_fcb  = (const float*)d_in[12];
  const float* m0_Wih  = (const float*)d_in[13];
  const float* m0_Whh  = (const float*)d_in[14];
  const float* m0_bih  = (const float*)d_in[15];
  const float* m0_bhh  = (const float*)d_in[16];
  const float* m1_Wih  = (const float*)d_in[17];
  const float* m1_Whh  = (const float*)d_in[18];
  const float* m1_bih  = (const float*)d_in[19];
  const float* m1_bhh  = (const float*)d_in[20];
  const float* m2_Wih  = (const float*)d_in[21];
  const float* m2_Whh  = (const float*)d_in[22];
  const float* m2_bih  = (const float*)d_in[23];
  const float* m2_bhh  = (const float*)d_in[24];
  const float* fcW     = (const float*)d_in[25];
  const float* fcb     = (const float*)d_in[26];

  char* ws = (char*)d_ws;
  size_t off = 0;
  auto take = [&](size_t b) -> void* {
    void* pp = ws + off;
    off = (off + b + 255) & ~(size_t)255;
    return pp;
  };
  half_t* WC_ROT = (half_t*)take((size_t)G4_ * 352 * 2);
  half_t* WC_TR  = (half_t*)take((size_t)G4_ * 352 * 2);
  half_t* WC_M0  = (half_t*)take((size_t)G4_ * 352 * 2);
  half_t* WC_M1  = (half_t*)take((size_t)G4_ * 512 * 2);
  half_t* WC_M2  = (half_t*)take((size_t)G4_ * 512 * 2);
  float* B_ROT = (float*)take((size_t)G4_ * 4);
  float* B_TR  = (float*)take((size_t)G4_ * 4);
  float* B_M0  = (float*)take((size_t)G4_ * 4);
  float* B_M1  = (float*)take((size_t)G4_ * 4);
  float* B_M2  = (float*)take((size_t)G4_ * 4);
  half_t* SEQB = (half_t*)take((size_t)2 * N_ * T_ * XP1_ * 2);
  float* HL_ROT = (float*)take((size_t)2 * N_ * H_ * 4);
  float* HL_TR  = (float*)take((size_t)2 * N_ * H_ * 4);
  float* HL_M2  = (float*)take((size_t)2 * N_ * H_ * 4);
  float* RT     = (float*)take((size_t)2 * N_ * 12 * 4);
  half_t* RINGP  = (half_t*)take((size_t)3 * 8 * 1024 * 32 * 2);
  half_t* RINGM0 = (half_t*)take((size_t)2 * 8 * 512 * 32 * 2);
  half_t* RINGM1 = (half_t*)take((size_t)2 * 8 * 512 * 32 * 2);
  half_t* RINGM2 = (half_t*)take((size_t)2 * 8 * 512 * 32 * 2);
  unsigned int* FLAGS = (unsigned int*)take((size_t)24 * 32 * sizeof(unsigned int));
  half_t* HS0 = (half_t*)take((size_t)T_ * 512 * H_ * 2);
  half_t* HS1 = (half_t*)take((size_t)T_ * 512 * H_ * 2);

  // p1 sentinel ring pre-fill; ml flags zeroed
  hipMemsetAsync(RINGP, 0xFF, (size_t)3 * 8 * 1024 * 32 * 2, stream);
  hipMemsetAsync(FLAGS, 0, (size_t)24 * 32 * sizeof(unsigned int), stream);

  // ---- pack weights (fp16) + fused biases ----
  pack_wcat<<<1408, 256, 0, stream>>>(rot_Whh, rot_Wih, rot_bih, rot_bhh, WC_ROT, B_ROT, IN_, 352);
  pack_wcat<<<1408, 256, 0, stream>>>(tr_Whh, tr_Wih, tr_bih, tr_bhh, WC_TR, B_TR, IN_, 352);
  pack_wcat<<<1408, 256, 0, stream>>>(m0_Whh, m0_Wih, m0_bih, m0_bhh, WC_M0, B_M0, IN_, 352);
  pack_wcat<<<2048, 256, 0, stream>>>(m1_Whh, m1_Wih, m1_bih, m1_bhh, WC_M1, B_M1, H_, 512);
  pack_wcat<<<2048, 256, 0, stream>>>(m2_Whh, m2_Wih, m2_bih, m2_bhh, WC_M2, B_M2, H_, 512);

  pack_seq<<<(2 * N_ * T_ * XP1_ + 255) / 256, 256, 0, stream>>>(x, SEQB);

  // ---- phase 1: rot & tr (proven sentinel protocol) ----
  lstm_p1<<<256, 256, 0, stream>>>(WC_ROT, WC_TR, B_ROT, B_TR, SEQB, RINGP, HL_ROT, HL_TR);

  fc3_rot<<<2, 256, 0, stream>>>(HL_ROT, HL_TR, rot_fcW, rot_fcb, tr_fcW, tr_fcb, RT);
  transform_seq<<<(2 * N_ * T_ * V_ + 255) / 256, 256, 0, stream>>>(x, RT, SEQB);

  // ---- fused m0/m1/m2 wavefront pipeline: LDS-staged panels + reg weights ----
  lstm_ml512<<<192, 512, 0, stream>>>(
      WC_M0, B_M0, WC_M1, B_M1, WC_M2, B_M2,
      SEQB, HS0, HS1, RINGM0, RINGM1, RINGM2, FLAGS, HL_M2);

  final_fc<<<256, 64, 0, stream>>>(HL_M2, fcW, fcb, (float*)d_out);
}